// Round 9
// baseline (418.755 us; speedup 1.0000x reference)
//
#include <hip/hip_runtime.h>
#include <hip/hip_bf16.h>

#define N_NODES 50000
#define N_EDGES 640000
#define HID 128
#define NBGRID 196

typedef float f32x4 __attribute__((ext_vector_type(4)));
typedef short s16x8 __attribute__((ext_vector_type(8)));
typedef __hip_bfloat16 bf16;

// ---- helpers ---------------------------------------------------------------
__device__ __forceinline__ s16x8 ld_frag_lds(const bf16* p) {
  union { uint2 u[2]; s16x8 v; } r;
  r.u[0] = *(const uint2*)(p);
  r.u[1] = *(const uint2*)(p + 4);
  return r.v;
}
__device__ __forceinline__ s16x8 ld_frag_g(const bf16* p) {
  union { uint4 u; s16x8 v; } r;
  r.u = *(const uint4*)(p);
  return r.v;
}
__device__ __forceinline__ f32x4 ld_f4(const float* p) { return *(const f32x4*)p; }
// fast sigmoid: raw v_rcp (1 ulp) instead of IEEE div — saves ~3 ops/use
__device__ __forceinline__ float sigm(float v) {
  return __builtin_amdgcn_rcpf(1.f + __expf(-v));
}
__device__ __forceinline__ float tanh_fast(float x) {
  return 1.f - 2.f * __builtin_amdgcn_rcpf(__expf(2.f * x) + 1.f);
}
__device__ __forceinline__ float b2f(unsigned short u) {
  return __uint_as_float(((unsigned)u) << 16);
}
// packed f32x2 -> bf16x2 (single v_cvt_pk_bf16_f32 on gfx950)
#if defined(__has_builtin)
#if __has_builtin(__builtin_amdgcn_cvt_pk_bf16_f32)
#define HAS_PK_BF16 1
#endif
#endif
__device__ __forceinline__ unsigned pk_bf16(float a, float b) {
#ifdef HAS_PK_BF16
  typedef __bf16 bf16x2_t __attribute__((ext_vector_type(2)));
  bf16x2_t r = __builtin_amdgcn_cvt_pk_bf16_f32(a, b);
  unsigned u;
  __builtin_memcpy(&u, &r, 4);
  return u;
#else
  union { bf16 h[2]; unsigned u; } o;
  o.h[0] = __float2bfloat16(a);
  o.h[1] = __float2bfloat16(b);
  return o.u;
#endif
}
// 8 consecutive f32 -> bf16x8 frag (in-register cvt; same RTNE as cvt pass)
__device__ __forceinline__ s16x8 ld_frag_f32(const float* p) {
  f32x4 v0 = ld_f4(p), v1 = ld_f4(p + 4);
  union { unsigned u[4]; s16x8 v; } r;
  r.u[0] = pk_bf16(v0[0], v0[1]);
  r.u[1] = pk_bf16(v0[2], v0[3]);
  r.u[2] = pk_bf16(v1[0], v1[1]);
  r.u[3] = pk_bf16(v1[2], v1[3]);
  return r.v;
}

// ---- prep kernels ----------------------------------------------------------
__global__ void cvt_kernel(const float* __restrict__ src, bf16* __restrict__ dst, int n) {
  int i = blockIdx.x * 256 + threadIdx.x;
  if (i < n) dst[i] = __float2bfloat16(src[i]);
}
__global__ void copy_x_kernel(const float* __restrict__ src, float* __restrict__ dst, int n) {
  int i = blockIdx.x * 256 + threadIdx.x;
  if (i < n) dst[i] = src[i];
}
// fp32 [K x 128] -> bf16 frag pack [kc][x][kk]
__device__ __forceinline__ void pack_one(const float* __restrict__ src,
                                         bf16* __restrict__ dst, int K, int i) {
  int kk = i & 31;
  int n  = (i >> 5) & 127;
  int kc = i >> 12;
  int k  = kc * 32 + kk;
  float v = (k < K) ? src[(size_t)k * HID + n] : 0.f;
  dst[i] = __float2bfloat16(v);
}
// merged: weight packs | weight folding | dst histogram
__global__ void cvtpack_kernel(const float* __restrict__ em_w1,
                               const float* __restrict__ nm_w1,
                               const float* __restrict__ nm_w2,
                               const float* __restrict__ em_w2,
                               const float* __restrict__ xm_w1,
                               const float* __restrict__ em_b2,
                               const float* __restrict__ ei_w,
                               const float* __restrict__ ei_b,
                               const float* __restrict__ xm_b1,
                               bf16* __restrict__ w1p,
                               bf16* __restrict__ nw1p,
                               bf16* __restrict__ nw2p,
                               bf16* __restrict__ xw1p,
                               float* __restrict__ efold,
                               float* __restrict__ bxv,
                               float* __restrict__ vqv,
                               const int* __restrict__ edst, int* __restrict__ cnt) {
  const int bid = blockIdx.x;
  const int tid = threadIdx.x;
  if (bid < 272) {
    int gid = bid * 256 + tid;
    if      (gid < 36864)  pack_one(em_w1, w1p, 273, gid);
    else if (gid < 53248)  pack_one(nm_w1 + 128 * HID, nw1p + 4 * 4096, 128, gid - 36864);
    else if (gid < 69632)  pack_one(nm_w2, nw2p, 128, gid - 53248);
    return;
  }
  if (bid < 402) {
    const int f = bid - 272;           // 0..129
    const int m = tid & 127, half = tid >> 7;
    if (f < 64) {                      // Wx rows r = f*2 + half
      const int r = f * 2 + half;
      float a = 0.f;
      const float* wr = em_w2 + r * HID;
      for (int j = 0; j < 128; ++j) a += wr[j] * xm_w1[j * HID + m];
      xw1p[(size_t)(((r >> 5) * 128 + m) * 32 + (r & 31))] = __float2bfloat16(a);
    } else if (f < 128) {              // Wq rows
      const int r = (f - 64) * 2 + half;
      float a = 0.f;
      const float* wr = em_w2 + r * HID;
      for (int j = 0; j < 128; ++j) a += wr[j] * nm_w1[j * HID + m];
      nw1p[(size_t)(((r >> 5) * 128 + m) * 32 + (r & 31))] = __float2bfloat16(a);
    } else if (f == 128) {             // efold
      if (tid < 128) {
        float a = 0.f;
        const float* wr = em_w2 + m * HID;
        for (int j = 0; j < 128; ++j) a += wr[j] * ei_w[j];
        efold[m] = a;
        if (m == 0) {
          float e = ei_b[0];
          for (int j = 0; j < 128; ++j) e += em_b2[j] * ei_w[j];
          efold[128] = e;
        }
      }
    } else {                           // bxv / vqv
      if (tid < 128) {
        float a = xm_b1[m], v = 0.f;
        for (int j = 0; j < 128; ++j) {
          a += em_b2[j] * xm_w1[j * HID + m];
          v += em_b2[j] * nm_w1[j * HID + m];
        }
        bxv[m] = a; vqv[m] = v;
      }
    }
    return;
  }
  if (cnt != nullptr) {
    int e = (bid - 402) * 256 + tid;
    if (e < N_EDGES) atomicAdd(&cnt[edst[e]], 1);
  }
}

// ---- node projection: pab[n] = [ h@W1a | h@W1b ] (bf16), f32 src, no LDS ---
__global__ __launch_bounds__(256, 4)
void proj_kernel(const float* __restrict__ h, const bf16* __restrict__ w1p,
                 bf16* __restrict__ pab) {
  const int tid = threadIdx.x;
  const int n0 = blockIdx.x * 64;
  const int lane = tid & 63, wv = tid >> 6;
  const int tbl = wv >> 1;            // 0 = Pa (W rows 0..127), 1 = Pb (128..255)
  const int mbase = (wv & 1) * 64;
  const int q = lane >> 4, ml = lane & 15;

  int nrow[4];
#pragma unroll
  for (int nt = 0; nt < 4; ++nt) {
    int n = n0 + nt * 16 + ml;
    nrow[nt] = (n < N_NODES) ? n : (N_NODES - 1);
  }

  const f32x4 zf = {0.f, 0.f, 0.f, 0.f};
  f32x4 acc[4][4];
#pragma unroll
  for (int a = 0; a < 4; ++a)
#pragma unroll
    for (int b = 0; b < 4; ++b) acc[a][b] = zf;

#pragma unroll
  for (int kc = 0; kc < 4; ++kc) {
    s16x8 bn[4];
#pragma unroll
    for (int nt = 0; nt < 4; ++nt)
      bn[nt] = ld_frag_f32(h + (size_t)nrow[nt] * HID + kc * 32 + q * 8);
#pragma unroll
    for (int mt = 0; mt < 4; ++mt) {
      s16x8 aw = ld_frag_g(w1p + (size_t)((tbl * 4 + kc) * HID + mbase + mt * 16 + ml) * 32 + q * 8);
#pragma unroll
      for (int nt = 0; nt < 4; ++nt)
        acc[mt][nt] = __builtin_amdgcn_mfma_f32_16x16x32_bf16(aw, bn[nt], acc[mt][nt], 0, 0, 0);
    }
  }
#pragma unroll
  for (int mt = 0; mt < 4; ++mt) {
    const int m0 = mbase + mt * 16 + q * 4;
#pragma unroll
    for (int nt = 0; nt < 4; ++nt) {
      const int nn = n0 + nt * 16 + ml;
      if (nn < N_NODES) {
        uint2 o;
        o.x = pk_bf16(acc[mt][nt][0], acc[mt][nt][1]);
        o.y = pk_bf16(acc[mt][nt][2], acc[mt][nt][3]);
        *(uint2*)(pab + (size_t)nn * 256 + tbl * 128 + m0) = o;
      }
    }
  }
}

// ---- fused scan (histogram/scatter stay full-width) ------------------------
__device__ __forceinline__ void gsync(int* bar, int phase) {
  __syncthreads();
  if (threadIdx.x == 0) {
    __threadfence();
    atomicAdd(&bar[phase], 1);
    while (atomicAdd(&bar[phase], 0) < NBGRID) __builtin_amdgcn_s_sleep(4);
    __threadfence();
  }
  __syncthreads();
}

__global__ __launch_bounds__(256)
void scan_kernel(const int* __restrict__ cnt, int* __restrict__ ptr,
                 int* __restrict__ work, int* __restrict__ bsum,
                 int* __restrict__ boff, int* __restrict__ bar) {
  __shared__ int s[256];
  const int tid = threadIdx.x, bid = blockIdx.x;
  const int i = bid * 256 + tid;
  int v = (i < N_NODES) ? cnt[i] : 0;
  s[tid] = v;
  __syncthreads();
  for (int off = 1; off < 256; off <<= 1) {
    int t = (tid >= off) ? s[tid - off] : 0;
    __syncthreads();
    s[tid] += t;
    __syncthreads();
  }
  const int myp = s[tid] - v;           // exclusive within block (kept in reg)
  if (tid == 255) bsum[bid] = s[255];
  gsync(bar, 0);
  if (bid == 0) {
    int v2 = (tid < NBGRID) ? bsum[tid] : 0;
    s[tid] = v2;
    __syncthreads();
    for (int off = 1; off < 256; off <<= 1) {
      int t = (tid >= off) ? s[tid - off] : 0;
      __syncthreads();
      s[tid] += t;
      __syncthreads();
    }
    if (tid < NBGRID) boff[tid] = s[tid] - v2;
    if (tid == NBGRID - 1) boff[NBGRID] = s[tid];
  }
  gsync(bar, 1);
  if (i < N_NODES) {
    int p = myp + boff[bid];
    ptr[i] = p;
    work[i] = p;
  }
  if (i == 0) ptr[N_NODES] = boff[NBGRID];
}

// ---- scatter: single int4 stream {dst, src, edge, 0} at sorted position ----
__global__ void scatter_kernel(const int* __restrict__ esrc, const int* __restrict__ edst,
                               int* __restrict__ work, int4* __restrict__ esw) {
  int e = blockIdx.x * 256 + threadIdx.x;
  if (e < N_EDGES) {
    int d = edst[e];
    int p = atomicAdd(&work[d], 1);
    esw[p] = make_int4(d, esrc[e], e, 0);
  }
}

// ---- fused edge kernel (64-edge tile, 256 threads, ~20KB LDS) --------------
// Half tile of the r4 kernel: same 4-wave shape, half the LDS -> 8 blocks/CU
// (32 waves/CU at VGPR<=64). stage1 = identity-pair MFMA (Pa+Pb) + feat chunk;
// eij folded; x-gate from t1@Wx; reduce q = sum eij*t1, s = sum eij.
template<int MODE>
__global__ __launch_bounds__(256, 8)
void edge_kernel(const bf16* __restrict__ pab, const float* __restrict__ x,
                 const int* __restrict__ srci, const int* __restrict__ dsti,
                 const int4* __restrict__ esw, const int* __restrict__ ptr,
                 const float* __restrict__ eattr,
                 const bf16* __restrict__ w1p, const bf16* __restrict__ xw1p,
                 const float* __restrict__ em_b1, const float* __restrict__ efold,
                 const float* __restrict__ bxv, const float* __restrict__ xm_w2,
                 float* __restrict__ q_f32, float* __restrict__ xout,
                 bf16* __restrict__ qb, float* __restrict__ s_arr,
                 float* __restrict__ headrec, float* __restrict__ tailrec,
                 float* __restrict__ headx, float* __restrict__ tailx) {
  __shared__ float arena[4930];
  bf16*  const smem  = (bf16*)arena;          // Abuf(64x36) / Tbuf(64x132)
  float* const rxL   = arena + 4224;          // pre-scaled by invd
  float* const ryL   = arena + 4288;
  float* const rzL   = arena + 4352;
  float* const eijL  = arena + 4416;
  float* const epart = arena + 4480;          // [2][64]
  float* const xpart = arena + 4608;          // [2][64]
  int*   const dstL     = (int*)(arena + 4736);  // 64
  int*   const segstart = (int*)(arena + 4800);  // 65
  int*   const segmode  = (int*)(arena + 4865);  // 64
  int*   const nseg_p   = (int*)(arena + 4929);
  bf16*  const Abuf = smem;
  bf16*  const Tbuf = smem;

  const int tid = threadIdx.x;
  const int e0  = blockIdx.x * 64;
  const int lane = tid & 63, wv = tid >> 6;
  const int wrow = wv >> 1, wcol = wv & 1;
  const int q = lane >> 4, ml = lane & 15;
  const int mbase = wrow * 64, nbase = wcol * 32;

  // preamble: 4 threads/edge (8 bf16 of the 32-col feat row each)
  const int se = tid >> 2, sh = tid & 3;       // se 0..63
  const int pos = e0 + se;
  int sdst, ssrc, eg;
  if (MODE == 1) {
    const int4 dd = esw[pos];
    sdst = dd.x; ssrc = dd.y; eg = dd.z;
  } else {
    sdst = dsti[pos]; ssrc = srci[pos]; eg = pos;
  }
  if (sh == 0) dstL[se] = sdst;

  // ---- identity-pair A-frag: A(m,k) = [k==m] + [k==m+16] -------------------
  const int jpos = ml & 7, qsel = ml >> 3;
  const bool rowsel = (q == qsel) || (q == 2 + qsel);
  union { unsigned u[4]; s16x8 v; } iden;
#pragma unroll
  for (int jj = 0; jj < 4; ++jj) {
    unsigned w0 = (rowsel && (jpos == 2 * jj))     ? 0x3F80u : 0u;
    unsigned w1 = (rowsel && (jpos == 2 * jj + 1)) ? 0x3F80u : 0u;
    iden.u[jj] = w0 | (w1 << 16);
  }

  // ---- gather raw bf16 B-frags of Pa/Pb (16B per lane per (nt,mt)) ---------
  s16x8 bfr[2][4];
#pragma unroll
  for (int nt = 0; nt < 2; ++nt) {
    const int ed = e0 + nbase + nt * 16 + ml;
    int nodei;
    if (MODE == 1) {
      const int2 dd = *(const int2*)(esw + ed);
      nodei = (q < 2) ? dd.x : dd.y;
    } else {
      nodei = (q < 2) ? dsti[ed] : srci[ed];
    }
    const bf16* pb = pab + (size_t)nodei * 256 + ((q >> 1) << 7) + mbase + ((q & 1) << 3);
#pragma unroll
    for (int mt = 0; mt < 4; ++mt)
      bfr[nt][mt] = ld_frag_g(pb + mt * 16);
  }

  // ---- edge features + rel-x (overlaps gather latency); 8 bf16/thread ------
  union U8 { bf16 h[8]; uint2 u[2]; } p8;
  {
    const float* ap = eattr + (size_t)eg * 16;
    if (sh == 0) {
      const float* xd = x + 3 * sdst;
      const float* xs = x + 3 * ssrc;
      float dx = xd[0] - xs[0], dy = xd[1] - xs[1], dz = xd[2] - xs[2];
      float dsq = dx * dx + dy * dy + dz * dz;
      float invd = 1.f / (sqrtf(dsq + 1e-8f) + 1.f);
      rxL[se] = dx * invd; ryL[se] = dy * invd; rzL[se] = dz * invd;
      p8.h[0] = __float2bfloat16(dsq);
#pragma unroll
      for (int j = 0; j < 7; ++j) p8.h[1 + j] = __float2bfloat16(ap[j]);
    } else if (sh == 1) {
#pragma unroll
      for (int j = 0; j < 8; ++j) p8.h[j] = __float2bfloat16(ap[7 + j]);
    } else if (sh == 2) {
      p8.h[0] = __float2bfloat16(ap[15]);
#pragma unroll
      for (int j = 1; j < 8; ++j) p8.h[j] = __float2bfloat16(0.f);
    } else {
#pragma unroll
      for (int j = 0; j < 8; ++j) p8.h[j] = __float2bfloat16(0.f);
    }
  }
  {
    bf16* d = Abuf + se * 36 + sh * 8;
    ((uint2*)d)[0] = p8.u[0];
    ((uint2*)d)[1] = p8.u[1];
  }

  // ---- stage 1 part A: Pa+Pb via identity-pair MFMA (matrix pipe) ----------
  const f32x4 zf = {0.f, 0.f, 0.f, 0.f};
  f32x4 acc[4][2];
#pragma unroll
  for (int a = 0; a < 4; ++a)
#pragma unroll
    for (int b = 0; b < 2; ++b) acc[a][b] = zf;
#pragma unroll
  for (int nt = 0; nt < 2; ++nt)
#pragma unroll
    for (int mt = 0; mt < 4; ++mt)
      acc[mt][nt] = __builtin_amdgcn_mfma_f32_16x16x32_bf16(iden.v, bfr[nt][mt], acc[mt][nt], 0, 0, 0);
  __syncthreads();   // A: Abuf + dstL + rel-x visible

  // ---- stage 1 part B: feat chunk (K=32), A-frags from w1p chunk 8 ---------
  {
    s16x8 be[2];
#pragma unroll
    for (int nt = 0; nt < 2; ++nt)
      be[nt] = ld_frag_lds(Abuf + (nbase + nt * 16 + ml) * 36 + q * 8);
#pragma unroll
    for (int mt = 0; mt < 4; ++mt) {
      s16x8 aw = ld_frag_g(w1p + (size_t)(8 * HID + mbase + mt * 16 + ml) * 32 + q * 8);
#pragma unroll
      for (int nt = 0; nt < 2; ++nt)
        acc[mt][nt] = __builtin_amdgcn_mfma_f32_16x16x32_bf16(aw, be[nt], acc[mt][nt], 0, 0, 0);
    }
  }
  __syncthreads();   // B: Abuf reads done before Tbuf overwrite

  // epilogue 1: +b1, silu -> Tbuf; eij partials from folded vector (free)
  {
    float pe[2] = {0.f, 0.f};
#pragma unroll
    for (int mt = 0; mt < 4; ++mt) {
      const int m0 = mbase + mt * 16 + q * 4;
      const f32x4 b1v = ld_f4(em_b1 + m0);
      const f32x4 efv = ld_f4(efold + m0);
#pragma unroll
      for (int nt = 0; nt < 2; ++nt) {
        const int e = nbase + nt * 16 + ml;
        float v0 = acc[mt][nt][0] + b1v[0]; v0 *= sigm(v0);
        float v1 = acc[mt][nt][1] + b1v[1]; v1 *= sigm(v1);
        float v2 = acc[mt][nt][2] + b1v[2]; v2 *= sigm(v2);
        float v3 = acc[mt][nt][3] + b1v[3]; v3 *= sigm(v3);
        pe[nt] += v0 * efv[0] + v1 * efv[1] + v2 * efv[2] + v3 * efv[3];
        uint2 o;
        o.x = pk_bf16(v0, v1);
        o.y = pk_bf16(v2, v3);
        *(uint2*)(Tbuf + e * 132 + m0) = o;
      }
    }
#pragma unroll
    for (int nt = 0; nt < 2; ++nt) {
      pe[nt] += __shfl_xor(pe[nt], 16);
      pe[nt] += __shfl_xor(pe[nt], 32);
    }
    if (lane < 16) {
#pragma unroll
      for (int nt = 0; nt < 2; ++nt)
        epart[wrow * 64 + nbase + nt * 16 + ml] = pe[nt];
    }
  }
  __syncthreads();   // C: Tbuf(t1) + epart visible

  if (tid < 64) eijL[tid] = sigm(epart[tid] + epart[64 + tid] + efold[128]);

  // ---------------- x branch: xh' = Wx^T (x) t1^T (folded weights) ---------
#pragma unroll
  for (int a = 0; a < 4; ++a)
#pragma unroll
    for (int b = 0; b < 2; ++b) acc[a][b] = zf;
  for (int kc = 0; kc < 4; ++kc) {
    s16x8 bt[2];
#pragma unroll
    for (int nt = 0; nt < 2; ++nt)
      bt[nt] = ld_frag_lds(Tbuf + (nbase + nt * 16 + ml) * 132 + kc * 32 + q * 8);
#pragma unroll
    for (int mt = 0; mt < 4; ++mt) {
      s16x8 aw = ld_frag_g(xw1p + (size_t)(kc * HID + mbase + mt * 16 + ml) * 32 + q * 8);
#pragma unroll
      for (int nt = 0; nt < 2; ++nt)
        acc[mt][nt] = __builtin_amdgcn_mfma_f32_16x16x32_bf16(aw, bt[nt], acc[mt][nt], 0, 0, 0);
    }
  }
  {
    float px[2] = {0.f, 0.f};
#pragma unroll
    for (int mt = 0; mt < 4; ++mt) {
      const int m0 = mbase + mt * 16 + q * 4;
      const f32x4 xbv = ld_f4(bxv + m0);
      const f32x4 wv2 = ld_f4(xm_w2 + m0);
#pragma unroll
      for (int nt = 0; nt < 2; ++nt)
#pragma unroll
        for (int r = 0; r < 4; ++r) {
          float v = acc[mt][nt][r] + xbv[r];
          v *= sigm(v);
          px[nt] += v * wv2[r];
        }
    }
#pragma unroll
    for (int nt = 0; nt < 2; ++nt) {
      px[nt] += __shfl_xor(px[nt], 16);
      px[nt] += __shfl_xor(px[nt], 32);
    }
    if (lane < 16) {
#pragma unroll
      for (int nt = 0; nt < 2; ++nt)
        xpart[wrow * 64 + nbase + nt * 16 + ml] = px[nt];
    }
  }
  __syncthreads();   // D: xpart + eijL visible

  if (tid < 64) {
    const float g = tanh_fast(xpart[tid] + xpart[64 + tid]);
    rxL[tid] *= g; ryL[tid] *= g; rzL[tid] *= g;   // rxL already includes invd
  }

  if (MODE == 0) {
    __syncthreads();
    const float ev = eijL[se];
    const unsigned short* tr = (const unsigned short*)Tbuf + se * 132 + sh * 32;
    float* mp = q_f32 + (size_t)sdst * HID + sh * 32;
#pragma unroll
    for (int j = 0; j < 32; ++j)
      unsafeAtomicAdd(mp + j, b2f(tr[j]) * ev);
    if (tid < 64) {
      int dn = dstL[tid];
      unsafeAtomicAdd(&s_arr[dn], eijL[tid]);
      unsafeAtomicAdd(xout + dn * 3 + 0, rxL[tid]);
      unsafeAtomicAdd(xout + dn * 3 + 1, ryL[tid]);
      unsafeAtomicAdd(xout + dn * 3 + 2, rzL[tid]);
    }
    return;
  }

  // ---------------- MODE 1: in-block segmented reduction (64 rows) ----------
  if (wv == 0) {
    const bool flag = (lane == 0) || (dstL[lane] != dstL[lane - 1]);
    const unsigned long long mask = __ballot(flag);
    const unsigned long long ltm = (1ULL << lane) - 1;
    if (flag) segstart[__popcll(mask & ltm)] = lane;
    if (lane == 0) {
      int ns = (int)__popcll(mask);
      nseg_p[0] = ns;
      segstart[ns] = 64;
    }
  }
  __syncthreads();
  const int nseg = nseg_p[0];
  if (tid < nseg) {
    const int r0 = segstart[tid], r1 = segstart[tid + 1];
    const int d  = dstL[r0];
    const int p0 = ptr[d], p1 = ptr[d + 1];
    const bool lX = p0 < e0 + r0;
    const bool rX = p1 > e0 + r1;
    segmode[tid] = (!lX && !rX) ? 0 : (rX ? 2 : 1);
  }
  __syncthreads();

  // q: per (segment, 4-col group) sum of eij*t1 — uint2 LDS reads
  for (int t = tid; t < (nseg << 5); t += 256) {
    const int s = t >> 5, c4 = (t & 31) * 4;
    const int r0 = segstart[s], r1 = segstart[s + 1];
    float a0 = 0.f, a1 = 0.f, a2 = 0.f, a3 = 0.f;
    for (int r = r0; r < r1; ++r) {
      const uint2 v = *(const uint2*)(Tbuf + r * 132 + c4);
      const float ev = eijL[r];
      a0 += __uint_as_float(v.x << 16) * ev;
      a1 += __uint_as_float(v.x & 0xffff0000u) * ev;
      a2 += __uint_as_float(v.y << 16) * ev;
      a3 += __uint_as_float(v.y & 0xffff0000u) * ev;
    }
    const int mode = segmode[s];
    if (mode == 0) {
      uint2 o;
      o.x = pk_bf16(a0, a1);
      o.y = pk_bf16(a2, a3);
      *(uint2*)(qb + (size_t)dstL[r0] * HID + c4) = o;
    } else if (mode == 2) {
      f32x4 o = {a0, a1, a2, a3};
      *(f32x4*)(tailrec + (size_t)blockIdx.x * HID + c4) = o;
    } else {
      f32x4 o = {a0, a1, a2, a3};
      *(f32x4*)(headrec + (size_t)blockIdx.x * HID + c4) = o;
    }
  }
  // x + s: per (segment, dim) sums; dim 3 = sum of eij
  for (int t = tid; t < (nseg << 2); t += 256) {
    const int s = t >> 2, d = t & 3;
    const int r0 = segstart[s], r1 = segstart[s + 1];
    float a = 0.f;
    if (d < 3) {
      const float* src = (d == 0) ? rxL : ((d == 1) ? ryL : rzL);
      for (int r = r0; r < r1; ++r) a += src[r];
    } else {
      for (int r = r0; r < r1; ++r) a += eijL[r];
    }
    const int mode = segmode[s];
    const int dn = dstL[r0];
    if (mode == 0) {
      if (d < 3) xout[dn * 3 + d] = x[dn * 3 + d] + a;
      else       s_arr[dn] = a;
    }
    else if (mode == 2) tailx[blockIdx.x * 4 + d] = a;
    else                headx[blockIdx.x * 4 + d] = a;
  }
}

// ---- node kernel (fused fix phase-0 + GEMMs; f32 h frags; Wq fold) ---------
__global__ __launch_bounds__(256, 6)
void node_kernel(bf16* __restrict__ qv, const float* __restrict__ h,
                 float* __restrict__ s_arr, const float* __restrict__ vqv,
                 const bf16* __restrict__ nw1p, const bf16* __restrict__ nw2p,
                 const float* __restrict__ nb1, const float* __restrict__ nb2,
                 const int* __restrict__ ptr,
                 const float* __restrict__ headrec, const float* __restrict__ tailrec,
                 const float* __restrict__ headx, const float* __restrict__ tailx,
                 const float* __restrict__ x, float* __restrict__ xout,
                 float* __restrict__ hout) {
  __shared__ bf16 Tbuf[64 * 132];
  const int tid = threadIdx.x;
  const int n0 = blockIdx.x * 64;

  // ---- phase 0 (sorted path only): fix spanning / deg-0 nodes of this block
  if (ptr != nullptr) {
    const int fn = n0 + (tid >> 2);
    const int fh = tid & 3;
    if (fn < N_NODES) {
      const int p0 = ptr[fn], p1 = ptr[fn + 1];
      if (p0 == p1) {
        const uint4 z = make_uint4(0u, 0u, 0u, 0u);
        uint4* qrow = (uint4*)(qv + (size_t)fn * HID + fh * 32);
        qrow[0] = z; qrow[1] = z; qrow[2] = z; qrow[3] = z;
        if (fh == 0) {
          xout[fn * 3 + 0] = x[fn * 3 + 0];
          xout[fn * 3 + 1] = x[fn * 3 + 1];
          xout[fn * 3 + 2] = x[fn * 3 + 2];
          s_arr[fn] = 0.f;
        }
      } else {
        const int B0 = p0 >> 6, B1 = (p1 - 1) >> 6;   // 64-edge blocks
        if (B0 != B1) {
          const int c0 = fh * 32;
          float a[32];
#pragma unroll
          for (int j = 0; j < 32; ++j) a[j] = 0.f;
          float xa0 = 0.f, xa1 = 0.f, xa2 = 0.f, xa3 = 0.f;
          for (int b = B0; b < B1; ++b) {
            const float* tr = tailrec + (size_t)b * HID + c0;
#pragma unroll
            for (int j8 = 0; j8 < 8; ++j8) {
              const f32x4 v = ld_f4(tr + j8 * 4);
              a[j8 * 4 + 0] += v[0]; a[j8 * 4 + 1] += v[1];
              a[j8 * 4 + 2] += v[2]; a[j8 * 4 + 3] += v[3];
            }
            if (fh == 0) {
              const f32x4 tx = ld_f4(tailx + b * 4);
              xa0 += tx[0]; xa1 += tx[1]; xa2 += tx[2]; xa3 += tx[3];
            }
          }
          const float* hr = headrec + (size_t)B1 * HID + c0;
#pragma unroll
          for (int j8 = 0; j8 < 8; ++j8) {
            const f32x4 v = ld_f4(hr + j8 * 4);
            a[j8 * 4 + 0] += v[0]; a[j8 * 4 + 1] += v[1];
            a[j8 * 4 + 2] += v[2]; a[j8 * 4 + 3] += v[3];
          }
          if (fh == 0) {
            const f32x4 hx = ld_f4(headx + B1 * 4);
            xa0 += hx[0]; xa1 += hx[1]; xa2 += hx[2]; xa3 += hx[3];
          }
          uint4* qrow = (uint4*)(qv + (size_t)fn * HID + c0);
#pragma unroll
          for (int j8 = 0; j8 < 4; ++j8) {
            uint4 o;
            o.x = pk_bf16(a[j8 * 8 + 0], a[j8 * 8 + 1]);
            o.y = pk_bf16(a[j8 * 8 + 2], a[j8 * 8 + 3]);
            o.z = pk_bf16(a[j8 * 8 + 4], a[j8 * 8 + 5]);
            o.w = pk_bf16(a[j8 * 8 + 6], a[j8 * 8 + 7]);
            qrow[j8] = o;
          }
          if (fh == 0) {
            xout[fn * 3 + 0] = x[fn * 3 + 0] + xa0;
            xout[fn * 3 + 1] = x[fn * 3 + 1] + xa1;
            xout[fn * 3 + 2] = x[fn * 3 + 2] + xa2;
            s_arr[fn] = xa3;
          }
        }
      }
    }
    __syncthreads();   // same-workgroup global writes visible to GEMM reads
  }

  const int lane = tid & 63, wv = tid >> 6;
  const int wrow = wv >> 1, wcol = wv & 1;
  const int q = lane >> 4, ml = lane & 15;
  const int mbase = wrow * 64, nbase = wcol * 32;

  int nrow[2];
#pragma unroll
  for (int nt = 0; nt < 2; ++nt) {
    int n = n0 + nbase + nt * 16 + ml;
    nrow[nt] = (n < N_NODES) ? n : (N_NODES - 1);
  }

  const f32x4 zf = {0.f, 0.f, 0.f, 0.f};
  f32x4 acc[4][2];
#pragma unroll
  for (int a = 0; a < 4; ++a)
#pragma unroll
    for (int b = 0; b < 2; ++b) acc[a][b] = zf;

#pragma unroll
  for (int c = 0; c < 8; ++c) {
    s16x8 bn[2];
#pragma unroll
    for (int nt = 0; nt < 2; ++nt) {
      if (c < 4)
        bn[nt] = ld_frag_g(qv + (size_t)nrow[nt] * HID + c * 32 + q * 8);
      else
        bn[nt] = ld_frag_f32(h + (size_t)nrow[nt] * HID + (c - 4) * 32 + q * 8);
    }
#pragma unroll
    for (int mt = 0; mt < 4; ++mt) {
      s16x8 aw = ld_frag_g(nw1p + (size_t)(c * HID + mbase + mt * 16 + ml) * 32 + q * 8);
#pragma unroll
      for (int nt = 0; nt < 2; ++nt)
        acc[mt][nt] = __builtin_amdgcn_mfma_f32_16x16x32_bf16(aw, bn[nt], acc[mt][nt], 0, 0, 0);
    }
  }
  // rank-1 bias-fold correction: acc += s[node] * vq[m]  (mi = q@W2 + s*b2)
  {
    const float sv0 = s_arr[nrow[0]], sv1 = s_arr[nrow[1]];
#pragma unroll
    for (int mt = 0; mt < 4; ++mt) {
      const int m0 = mbase + mt * 16 + q * 4;
      const f32x4 vqf = ld_f4(vqv + m0);
#pragma unroll
      for (int r = 0; r < 4; ++r) {
        acc[mt][0][r] += sv0 * vqf[r];
        acc[mt][1][r] += sv1 * vqf[r];
      }
    }
  }
#pragma unroll
  for (int mt = 0; mt < 4; ++mt) {
    const int m0 = mbase + mt * 16 + q * 4;
    const f32x4 b1v = ld_f4(nb1 + m0);
#pragma unroll
    for (int nt = 0; nt < 2; ++nt) {
      const int e = nbase + nt * 16 + ml;
      float v0 = acc[mt][nt][0] + b1v[0]; v0 *= sigm(v0);
      float v1 = acc[mt][nt][1] + b1v[1]; v1 *= sigm(v1);
      float v2 = acc[mt][nt][2] + b1v[2]; v2 *= sigm(v2);
      float v3 = acc[mt][nt][3] + b1v[3]; v3 *= sigm(v3);
      uint2 o;
      o.x = pk_bf16(v0, v1);
      o.y = pk_bf16(v2, v3);
      *(uint2*)(Tbuf + e * 132 + m0) = o;
    }
  }
  __syncthreads();
#pragma unroll
  for (int a = 0; a < 4; ++a)
#pragma unroll
    for (int b = 0; b < 2; ++b) acc[a][b] = zf;
  for (int kc = 0; kc < 4; ++kc) {
    s16x8 bt[2];
#pragma unroll
    for (int nt = 0; nt < 2; ++nt)
      bt[nt] = ld_frag_lds(Tbuf + (nbase + nt * 16 + ml) * 132 + kc * 32 + q * 8);
#pragma unroll
    for (int mt = 0; mt < 4; ++mt) {
      s16x8 aw = ld_frag_g(nw2p + (size_t)(kc * HID + mbase + mt * 16 + ml) * 32 + q * 8);
#pragma unroll
      for (int nt = 0; nt < 2; ++nt)
        acc[mt][nt] = __builtin_amdgcn_mfma_f32_16x16x32_bf16(aw, bt[nt], acc[mt][nt], 0, 0, 0);
    }
  }
#pragma unroll
  for (int mt = 0; mt < 4; ++mt) {
    const int m0 = mbase + mt * 16 + q * 4;
    const f32x4 b2v = ld_f4(nb2 + m0);
#pragma unroll
    for (int nt = 0; nt < 2; ++nt) {
      const int nn = n0 + nbase + nt * 16 + ml;
      if (nn < N_NODES) {
        const f32x4 hv = ld_f4(h + (size_t)nn * HID + m0);
        f32x4 o;
#pragma unroll
        for (int r = 0; r < 4; ++r) o[r] = hv[r] + acc[mt][nt][r] + b2v[r];
        *(f32x4*)(hout + (size_t)nn * HID + m0) = o;
      }
    }
  }
}

// ---- launcher --------------------------------------------------------------
extern "C" void kernel_launch(void* const* d_in, const int* in_sizes, int n_in,
                              void* d_out, int out_size, void* d_ws, size_t ws_size,
                              hipStream_t stream) {
  (void)in_sizes; (void)n_in; (void)out_size;
  const float* h     = (const float*)d_in[0];
  const float* x     = (const float*)d_in[1];
  const int*   eidx  = (const int*)  d_in[2];
  const float* eattr = (const float*)d_in[3];
  const float* em_w1 = (const float*)d_in[4];
  const float* em_b1 = (const float*)d_in[5];
  const float* em_w2 = (const float*)d_in[6];
  const float* em_b2 = (const float*)d_in[7];
  const float* ei_w  = (const float*)d_in[8];
  const float* ei_b  = (const float*)d_in[9];
  const float* xm_w1 = (const float*)d_in[10];
  const float* xm_b1 = (const float*)d_in[11];
  const float* xm_w2 = (const float*)d_in[12];
  const float* nm_w1 = (const float*)d_in[13];
  const float* nm_b1 = (const float*)d_in[14];
  const float* nm_w2 = (const float*)d_in[15];
  const float* nm_b2 = (const float*)d_in[16];

  float* hout = (float*)d_out;
  float* xout = hout + (size_t)N_NODES * HID;

  const int NBLK = N_EDGES / 64;               // 10000 (64-edge tiles)
  const int NPB  = (N_NODES + 63) / 64;        // 782

  char* w = (char*)d_ws;
  bf16* qb   = (bf16*)w;  w += (size_t)N_NODES * HID * 2;
  bf16* pab  = (bf16*)w;  w += (size_t)N_NODES * 256 * 2;
  bf16* w1p  = (bf16*)w;  w += 9 * HID * 32 * 2;
  bf16* xw1p = (bf16*)w;  w += 4 * HID * 32 * 2;
  bf16* nw1p = (bf16*)w;  w += 8 * HID * 32 * 2;
  bf16* nw2p = (bf16*)w;  w += 4 * HID * 32 * 2;
  float* efold = (float*)w;  w += 132 * 4;
  float* bxv   = (float*)w;  w += 128 * 4;
  float* vqv   = (float*)w;  w += 128 * 4;
  float* s_arr = (float*)w;  w += (size_t)N_NODES * 4;
  int* cnt   = (int*)w;   w += (size_t)N_NODES * 4;
  int* gbar  = (int*)w;   w += 16 * 4;
  int* work  = (int*)w;   w += (size_t)N_NODES * 4;
  int* ptr   = (int*)w;   w += (size_t)(N_NODES + 4) * 4;
  int4* esw  = (int4*)w;  w += (size_t)N_EDGES * 16;
  int* bsum  = (int*)w;   w += 256 * 4;
  int* boff  = (int*)w;   w += 256 * 4;
  float* headrec = (float*)w;  w += (size_t)NBLK * HID * 4;
  float* tailrec = (float*)w;  w += (size_t)NBLK * HID * 4;
  float* headx   = (float*)w;  w += (size_t)NBLK * 4 * 4;
  float* tailx   = (float*)w;  w += (size_t)NBLK * 4 * 4;
  float* q_f32   = (float*)w;  // fallback only
  size_t need_sorted = (size_t)(w - (char*)d_ws);
  const bool sorted = (ws_size >= need_sorted);

  if (sorted) {
    hipMemsetAsync(cnt, 0, (size_t)(N_NODES + 16) * 4, stream);   // cnt + gbar
    cvtpack_kernel<<<402 + 2500, 256, 0, stream>>>(
        em_w1, nm_w1, nm_w2, em_w2, xm_w1, em_b2, ei_w, ei_b, xm_b1,
        w1p, nw1p, nw2p, xw1p, efold, bxv, vqv, eidx + N_EDGES, cnt);
    proj_kernel<<<NPB, 256, 0, stream>>>(h, w1p, pab);
    scan_kernel<<<NBGRID, 256, 0, stream>>>(cnt, ptr, work, bsum, boff, gbar);
    scatter_kernel<<<(N_EDGES + 255) / 256, 256, 0, stream>>>(
        eidx, eidx + N_EDGES, work, esw);
    edge_kernel<1><<<NBLK, 256, 0, stream>>>(
        pab, x, nullptr, nullptr, esw, ptr, eattr, w1p, xw1p,
        em_b1, efold, bxv, xm_w2,
        nullptr, xout, qb, s_arr, headrec, tailrec, headx, tailx);
    node_kernel<<<NPB, 256, 0, stream>>>(
        qb, h, s_arr, vqv, nw1p, nw2p, nm_b1, nm_b2,
        ptr, headrec, tailrec, headx, tailx, x, xout, hout);
  } else {
    cvtpack_kernel<<<402, 256, 0, stream>>>(
        em_w1, nm_w1, nm_w2, em_w2, xm_w1, em_b2, ei_w, ei_b, xm_b1,
        w1p, nw1p, nw2p, xw1p, efold, bxv, vqv, nullptr, nullptr);
    proj_kernel<<<NPB, 256, 0, stream>>>(h, w1p, pab);
    hipMemsetAsync(q_f32, 0, (size_t)N_NODES * HID * 4, stream);
    hipMemsetAsync(s_arr, 0, (size_t)N_NODES * 4, stream);
    copy_x_kernel<<<(N_NODES * 3 + 255) / 256, 256, 0, stream>>>(x, xout, N_NODES * 3);
    edge_kernel<0><<<NBLK, 256, 0, stream>>>(
        pab, x, eidx, eidx + N_EDGES, nullptr, nullptr, eattr, w1p, xw1p,
        em_b1, efold, bxv, xm_w2,
        q_f32, xout, nullptr, s_arr, nullptr, nullptr, nullptr, nullptr);
    cvt_kernel<<<(N_NODES * HID + 255) / 256, 256, 0, stream>>>(q_f32, qb, N_NODES * HID);
    node_kernel<<<NPB, 256, 0, stream>>>(
        qb, h, s_arr, vqv, nw1p, nw2p, nm_b1, nm_b2,
        nullptr, nullptr, nullptr, nullptr, nullptr, x, xout, hout);
  }
}

// Round 10
// 399.524 us; speedup vs baseline: 1.0481x; 1.0481x over previous
//
#include <hip/hip_runtime.h>
#include <hip/hip_bf16.h>

#define N_NODES 50000
#define N_EDGES 640000
#define HID 128
#define NBGRID 196

typedef float f32x4 __attribute__((ext_vector_type(4)));
typedef short s16x8 __attribute__((ext_vector_type(8)));
typedef __hip_bfloat16 bf16;

// ---- helpers ---------------------------------------------------------------
__device__ __forceinline__ s16x8 ld_frag_lds(const bf16* p) {
  union { uint2 u[2]; s16x8 v; } r;
  r.u[0] = *(const uint2*)(p);
  r.u[1] = *(const uint2*)(p + 4);
  return r.v;
}
__device__ __forceinline__ s16x8 ld_frag_g(const bf16* p) {
  union { uint4 u; s16x8 v; } r;
  r.u = *(const uint4*)(p);
  return r.v;
}
__device__ __forceinline__ f32x4 ld_f4(const float* p) { return *(const f32x4*)p; }
// fast sigmoid: raw v_rcp (1 ulp) instead of IEEE div — saves ~3 ops/use
__device__ __forceinline__ float sigm(float v) {
  return __builtin_amdgcn_rcpf(1.f + __expf(-v));
}
__device__ __forceinline__ float tanh_fast(float x) {
  return 1.f - 2.f * __builtin_amdgcn_rcpf(__expf(2.f * x) + 1.f);
}
__device__ __forceinline__ float b2f(unsigned short u) {
  return __uint_as_float(((unsigned)u) << 16);
}
// packed f32x2 -> bf16x2 (single v_cvt_pk_bf16_f32 on gfx950)
#if defined(__has_builtin)
#if __has_builtin(__builtin_amdgcn_cvt_pk_bf16_f32)
#define HAS_PK_BF16 1
#endif
#endif
__device__ __forceinline__ unsigned pk_bf16(float a, float b) {
#ifdef HAS_PK_BF16
  typedef __bf16 bf16x2_t __attribute__((ext_vector_type(2)));
  bf16x2_t r = __builtin_amdgcn_cvt_pk_bf16_f32(a, b);
  unsigned u;
  __builtin_memcpy(&u, &r, 4);
  return u;
#else
  union { bf16 h[2]; unsigned u; } o;
  o.h[0] = __float2bfloat16(a);
  o.h[1] = __float2bfloat16(b);
  return o.u;
#endif
}
// 8 consecutive f32 -> bf16x8 frag (in-register cvt; same RTNE as cvt pass)
__device__ __forceinline__ s16x8 ld_frag_f32(const float* p) {
  f32x4 v0 = ld_f4(p), v1 = ld_f4(p + 4);
  union { unsigned u[4]; s16x8 v; } r;
  r.u[0] = pk_bf16(v0[0], v0[1]);
  r.u[1] = pk_bf16(v0[2], v0[3]);
  r.u[2] = pk_bf16(v1[0], v1[1]);
  r.u[3] = pk_bf16(v1[2], v1[3]);
  return r.v;
}

// ---- prep kernels ----------------------------------------------------------
__global__ void cvt_kernel(const float* __restrict__ src, bf16* __restrict__ dst, int n) {
  int i = blockIdx.x * 256 + threadIdx.x;
  if (i < n) dst[i] = __float2bfloat16(src[i]);
}
__global__ void copy_x_kernel(const float* __restrict__ src, float* __restrict__ dst, int n) {
  int i = blockIdx.x * 256 + threadIdx.x;
  if (i < n) dst[i] = src[i];
}
// fp32 [K x 128] -> bf16 frag pack [kc][x][kk]
__device__ __forceinline__ void pack_one(const float* __restrict__ src,
                                         bf16* __restrict__ dst, int K, int i) {
  int kk = i & 31;
  int n  = (i >> 5) & 127;
  int kc = i >> 12;
  int k  = kc * 32 + kk;
  float v = (k < K) ? src[(size_t)k * HID + n] : 0.f;
  dst[i] = __float2bfloat16(v);
}
// merged: weight packs | weight folding | dst histogram
__global__ void cvtpack_kernel(const float* __restrict__ em_w1,
                               const float* __restrict__ nm_w1,
                               const float* __restrict__ nm_w2,
                               const float* __restrict__ em_w2,
                               const float* __restrict__ xm_w1,
                               const float* __restrict__ em_b2,
                               const float* __restrict__ ei_w,
                               const float* __restrict__ ei_b,
                               const float* __restrict__ xm_b1,
                               bf16* __restrict__ w1p,
                               bf16* __restrict__ nw1p,
                               bf16* __restrict__ nw2p,
                               bf16* __restrict__ xw1p,
                               float* __restrict__ efold,
                               float* __restrict__ bxv,
                               float* __restrict__ vqv,
                               const int* __restrict__ edst, int* __restrict__ cnt) {
  const int bid = blockIdx.x;
  const int tid = threadIdx.x;
  if (bid < 272) {
    int gid = bid * 256 + tid;
    if      (gid < 36864)  pack_one(em_w1, w1p, 273, gid);
    else if (gid < 53248)  pack_one(nm_w1 + 128 * HID, nw1p + 4 * 4096, 128, gid - 36864);
    else if (gid < 69632)  pack_one(nm_w2, nw2p, 128, gid - 53248);
    return;
  }
  if (bid < 402) {
    const int f = bid - 272;           // 0..129
    const int m = tid & 127, half = tid >> 7;
    if (f < 64) {                      // Wx rows r = f*2 + half
      const int r = f * 2 + half;
      float a = 0.f;
      const float* wr = em_w2 + r * HID;
      for (int j = 0; j < 128; ++j) a += wr[j] * xm_w1[j * HID + m];
      xw1p[(size_t)(((r >> 5) * 128 + m) * 32 + (r & 31))] = __float2bfloat16(a);
    } else if (f < 128) {              // Wq rows
      const int r = (f - 64) * 2 + half;
      float a = 0.f;
      const float* wr = em_w2 + r * HID;
      for (int j = 0; j < 128; ++j) a += wr[j] * nm_w1[j * HID + m];
      nw1p[(size_t)(((r >> 5) * 128 + m) * 32 + (r & 31))] = __float2bfloat16(a);
    } else if (f == 128) {             // efold
      if (tid < 128) {
        float a = 0.f;
        const float* wr = em_w2 + m * HID;
        for (int j = 0; j < 128; ++j) a += wr[j] * ei_w[j];
        efold[m] = a;
        if (m == 0) {
          float e = ei_b[0];
          for (int j = 0; j < 128; ++j) e += em_b2[j] * ei_w[j];
          efold[128] = e;
        }
      }
    } else {                           // bxv / vqv
      if (tid < 128) {
        float a = xm_b1[m], v = 0.f;
        for (int j = 0; j < 128; ++j) {
          a += em_b2[j] * xm_w1[j * HID + m];
          v += em_b2[j] * nm_w1[j * HID + m];
        }
        bxv[m] = a; vqv[m] = v;
      }
    }
    return;
  }
  if (cnt != nullptr) {
    int e = (bid - 402) * 256 + tid;
    if (e < N_EDGES) atomicAdd(&cnt[edst[e]], 1);
  }
}

// ---- node projection: pab[n] = [ h@W1a | h@W1b ] (bf16), f32 src, no LDS ---
__global__ __launch_bounds__(256, 4)
void proj_kernel(const float* __restrict__ h, const bf16* __restrict__ w1p,
                 bf16* __restrict__ pab) {
  const int tid = threadIdx.x;
  const int n0 = blockIdx.x * 64;
  const int lane = tid & 63, wv = tid >> 6;
  const int tbl = wv >> 1;            // 0 = Pa (W rows 0..127), 1 = Pb (128..255)
  const int mbase = (wv & 1) * 64;
  const int q = lane >> 4, ml = lane & 15;

  int nrow[4];
#pragma unroll
  for (int nt = 0; nt < 4; ++nt) {
    int n = n0 + nt * 16 + ml;
    nrow[nt] = (n < N_NODES) ? n : (N_NODES - 1);
  }

  const f32x4 zf = {0.f, 0.f, 0.f, 0.f};
  f32x4 acc[4][4];
#pragma unroll
  for (int a = 0; a < 4; ++a)
#pragma unroll
    for (int b = 0; b < 4; ++b) acc[a][b] = zf;

#pragma unroll
  for (int kc = 0; kc < 4; ++kc) {
    s16x8 bn[4];
#pragma unroll
    for (int nt = 0; nt < 4; ++nt)
      bn[nt] = ld_frag_f32(h + (size_t)nrow[nt] * HID + kc * 32 + q * 8);
#pragma unroll
    for (int mt = 0; mt < 4; ++mt) {
      s16x8 aw = ld_frag_g(w1p + (size_t)((tbl * 4 + kc) * HID + mbase + mt * 16 + ml) * 32 + q * 8);
#pragma unroll
      for (int nt = 0; nt < 4; ++nt)
        acc[mt][nt] = __builtin_amdgcn_mfma_f32_16x16x32_bf16(aw, bn[nt], acc[mt][nt], 0, 0, 0);
    }
  }
#pragma unroll
  for (int mt = 0; mt < 4; ++mt) {
    const int m0 = mbase + mt * 16 + q * 4;
#pragma unroll
    for (int nt = 0; nt < 4; ++nt) {
      const int nn = n0 + nt * 16 + ml;
      if (nn < N_NODES) {
        uint2 o;
        o.x = pk_bf16(acc[mt][nt][0], acc[mt][nt][1]);
        o.y = pk_bf16(acc[mt][nt][2], acc[mt][nt][3]);
        *(uint2*)(pab + (size_t)nn * 256 + tbl * 128 + m0) = o;
      }
    }
  }
}

// ---- fused scan (histogram/scatter stay full-width) ------------------------
__device__ __forceinline__ void gsync(int* bar, int phase) {
  __syncthreads();
  if (threadIdx.x == 0) {
    __threadfence();
    atomicAdd(&bar[phase], 1);
    while (atomicAdd(&bar[phase], 0) < NBGRID) __builtin_amdgcn_s_sleep(4);
    __threadfence();
  }
  __syncthreads();
}

__global__ __launch_bounds__(256)
void scan_kernel(const int* __restrict__ cnt, int* __restrict__ ptr,
                 int* __restrict__ work, int* __restrict__ bsum,
                 int* __restrict__ boff, int* __restrict__ bar) {
  __shared__ int s[256];
  const int tid = threadIdx.x, bid = blockIdx.x;
  const int i = bid * 256 + tid;
  int v = (i < N_NODES) ? cnt[i] : 0;
  s[tid] = v;
  __syncthreads();
  for (int off = 1; off < 256; off <<= 1) {
    int t = (tid >= off) ? s[tid - off] : 0;
    __syncthreads();
    s[tid] += t;
    __syncthreads();
  }
  const int myp = s[tid] - v;           // exclusive within block (kept in reg)
  if (tid == 255) bsum[bid] = s[255];
  gsync(bar, 0);
  if (bid == 0) {
    int v2 = (tid < NBGRID) ? bsum[tid] : 0;
    s[tid] = v2;
    __syncthreads();
    for (int off = 1; off < 256; off <<= 1) {
      int t = (tid >= off) ? s[tid - off] : 0;
      __syncthreads();
      s[tid] += t;
      __syncthreads();
    }
    if (tid < NBGRID) boff[tid] = s[tid] - v2;
    if (tid == NBGRID - 1) boff[NBGRID] = s[tid];
  }
  gsync(bar, 1);
  if (i < N_NODES) {
    int p = myp + boff[bid];
    ptr[i] = p;
    work[i] = p;
  }
  if (i == 0) ptr[N_NODES] = boff[NBGRID];
}

// ---- scatter: single int4 stream {dst, src, edge, 0} at sorted position ----
__global__ void scatter_kernel(const int* __restrict__ esrc, const int* __restrict__ edst,
                               int* __restrict__ work, int4* __restrict__ esw) {
  int e = blockIdx.x * 256 + threadIdx.x;
  if (e < N_EDGES) {
    int d = edst[e];
    int p = atomicAdd(&work[d], 1);
    esw[p] = make_int4(d, esrc[e], e, 0);
  }
}

// ---- fused edge kernel (64-edge tile, 256 threads, ~20KB LDS) --------------
// Half tile of the r4 kernel: same 4-wave shape, half the LDS -> up to 8
// blocks/CU when VGPR<=64. stage1 = identity-pair MFMA (Pa+Pb) + feat chunk;
// eij folded; x-gate from t1@Wx; reduce q = sum eij*t1, s = sum eij.
// launch_bounds arg2 MUST be 4: arg2=8 caps VGPR at 32 -> scratch spills
// (r6: WRITE 107MB, r9: WRITE 71MB). arg2=4 -> natural 64-VGPR alloc, and
// actual occupancy is set by real VGPR+LDS (8 blocks/CU at <=64 VGPR).
template<int MODE>
__global__ __launch_bounds__(256, 4)
void edge_kernel(const bf16* __restrict__ pab, const float* __restrict__ x,
                 const int* __restrict__ srci, const int* __restrict__ dsti,
                 const int4* __restrict__ esw, const int* __restrict__ ptr,
                 const float* __restrict__ eattr,
                 const bf16* __restrict__ w1p, const bf16* __restrict__ xw1p,
                 const float* __restrict__ em_b1, const float* __restrict__ efold,
                 const float* __restrict__ bxv, const float* __restrict__ xm_w2,
                 float* __restrict__ q_f32, float* __restrict__ xout,
                 bf16* __restrict__ qb, float* __restrict__ s_arr,
                 float* __restrict__ headrec, float* __restrict__ tailrec,
                 float* __restrict__ headx, float* __restrict__ tailx) {
  __shared__ float arena[4930];
  bf16*  const smem  = (bf16*)arena;          // Abuf(64x36) / Tbuf(64x132)
  float* const rxL   = arena + 4224;          // pre-scaled by invd
  float* const ryL   = arena + 4288;
  float* const rzL   = arena + 4352;
  float* const eijL  = arena + 4416;
  float* const epart = arena + 4480;          // [2][64]
  float* const xpart = arena + 4608;          // [2][64]
  int*   const dstL     = (int*)(arena + 4736);  // 64
  int*   const segstart = (int*)(arena + 4800);  // 65
  int*   const segmode  = (int*)(arena + 4865);  // 64
  int*   const nseg_p   = (int*)(arena + 4929);
  bf16*  const Abuf = smem;
  bf16*  const Tbuf = smem;

  const int tid = threadIdx.x;
  const int e0  = blockIdx.x * 64;
  const int lane = tid & 63, wv = tid >> 6;
  const int wrow = wv >> 1, wcol = wv & 1;
  const int q = lane >> 4, ml = lane & 15;
  const int mbase = wrow * 64, nbase = wcol * 32;

  // preamble: 4 threads/edge (8 bf16 of the 32-col feat row each)
  const int se = tid >> 2, sh = tid & 3;       // se 0..63
  const int pos = e0 + se;
  int sdst, ssrc, eg;
  if (MODE == 1) {
    const int4 dd = esw[pos];
    sdst = dd.x; ssrc = dd.y; eg = dd.z;
  } else {
    sdst = dsti[pos]; ssrc = srci[pos]; eg = pos;
  }
  if (sh == 0) dstL[se] = sdst;

  // ---- identity-pair A-frag: A(m,k) = [k==m] + [k==m+16] -------------------
  const int jpos = ml & 7, qsel = ml >> 3;
  const bool rowsel = (q == qsel) || (q == 2 + qsel);
  union { unsigned u[4]; s16x8 v; } iden;
#pragma unroll
  for (int jj = 0; jj < 4; ++jj) {
    unsigned w0 = (rowsel && (jpos == 2 * jj))     ? 0x3F80u : 0u;
    unsigned w1 = (rowsel && (jpos == 2 * jj + 1)) ? 0x3F80u : 0u;
    iden.u[jj] = w0 | (w1 << 16);
  }

  // ---- gather raw bf16 B-frags of Pa/Pb (16B per lane per (nt,mt)) ---------
  s16x8 bfr[2][4];
#pragma unroll
  for (int nt = 0; nt < 2; ++nt) {
    const int ed = e0 + nbase + nt * 16 + ml;
    int nodei;
    if (MODE == 1) {
      const int2 dd = *(const int2*)(esw + ed);
      nodei = (q < 2) ? dd.x : dd.y;
    } else {
      nodei = (q < 2) ? dsti[ed] : srci[ed];
    }
    const bf16* pb = pab + (size_t)nodei * 256 + ((q >> 1) << 7) + mbase + ((q & 1) << 3);
#pragma unroll
    for (int mt = 0; mt < 4; ++mt)
      bfr[nt][mt] = ld_frag_g(pb + mt * 16);
  }

  // ---- edge features + rel-x (overlaps gather latency); 8 bf16/thread ------
  union U8 { bf16 h[8]; uint2 u[2]; } p8;
  {
    const float* ap = eattr + (size_t)eg * 16;
    if (sh == 0) {
      const float* xd = x + 3 * sdst;
      const float* xs = x + 3 * ssrc;
      float dx = xd[0] - xs[0], dy = xd[1] - xs[1], dz = xd[2] - xs[2];
      float dsq = dx * dx + dy * dy + dz * dz;
      float invd = 1.f / (sqrtf(dsq + 1e-8f) + 1.f);
      rxL[se] = dx * invd; ryL[se] = dy * invd; rzL[se] = dz * invd;
      p8.h[0] = __float2bfloat16(dsq);
#pragma unroll
      for (int j = 0; j < 7; ++j) p8.h[1 + j] = __float2bfloat16(ap[j]);
    } else if (sh == 1) {
#pragma unroll
      for (int j = 0; j < 8; ++j) p8.h[j] = __float2bfloat16(ap[7 + j]);
    } else if (sh == 2) {
      p8.h[0] = __float2bfloat16(ap[15]);
#pragma unroll
      for (int j = 1; j < 8; ++j) p8.h[j] = __float2bfloat16(0.f);
    } else {
#pragma unroll
      for (int j = 0; j < 8; ++j) p8.h[j] = __float2bfloat16(0.f);
    }
  }
  {
    bf16* d = Abuf + se * 36 + sh * 8;
    ((uint2*)d)[0] = p8.u[0];
    ((uint2*)d)[1] = p8.u[1];
  }

  // ---- stage 1 part A: Pa+Pb via identity-pair MFMA (matrix pipe) ----------
  const f32x4 zf = {0.f, 0.f, 0.f, 0.f};
  f32x4 acc[4][2];
#pragma unroll
  for (int a = 0; a < 4; ++a)
#pragma unroll
    for (int b = 0; b < 2; ++b) acc[a][b] = zf;
#pragma unroll
  for (int nt = 0; nt < 2; ++nt)
#pragma unroll
    for (int mt = 0; mt < 4; ++mt)
      acc[mt][nt] = __builtin_amdgcn_mfma_f32_16x16x32_bf16(iden.v, bfr[nt][mt], acc[mt][nt], 0, 0, 0);
  __syncthreads();   // A: Abuf + dstL + rel-x visible

  // ---- stage 1 part B: feat chunk (K=32), A-frags from w1p chunk 8 ---------
  {
    s16x8 be[2];
#pragma unroll
    for (int nt = 0; nt < 2; ++nt)
      be[nt] = ld_frag_lds(Abuf + (nbase + nt * 16 + ml) * 36 + q * 8);
#pragma unroll
    for (int mt = 0; mt < 4; ++mt) {
      s16x8 aw = ld_frag_g(w1p + (size_t)(8 * HID + mbase + mt * 16 + ml) * 32 + q * 8);
#pragma unroll
      for (int nt = 0; nt < 2; ++nt)
        acc[mt][nt] = __builtin_amdgcn_mfma_f32_16x16x32_bf16(aw, be[nt], acc[mt][nt], 0, 0, 0);
    }
  }
  __syncthreads();   // B: Abuf reads done before Tbuf overwrite

  // epilogue 1: +b1, silu -> Tbuf; eij partials from folded vector (free)
  {
    float pe[2] = {0.f, 0.f};
#pragma unroll
    for (int mt = 0; mt < 4; ++mt) {
      const int m0 = mbase + mt * 16 + q * 4;
      const f32x4 b1v = ld_f4(em_b1 + m0);
      const f32x4 efv = ld_f4(efold + m0);
#pragma unroll
      for (int nt = 0; nt < 2; ++nt) {
        const int e = nbase + nt * 16 + ml;
        float v0 = acc[mt][nt][0] + b1v[0]; v0 *= sigm(v0);
        float v1 = acc[mt][nt][1] + b1v[1]; v1 *= sigm(v1);
        float v2 = acc[mt][nt][2] + b1v[2]; v2 *= sigm(v2);
        float v3 = acc[mt][nt][3] + b1v[3]; v3 *= sigm(v3);
        pe[nt] += v0 * efv[0] + v1 * efv[1] + v2 * efv[2] + v3 * efv[3];
        uint2 o;
        o.x = pk_bf16(v0, v1);
        o.y = pk_bf16(v2, v3);
        *(uint2*)(Tbuf + e * 132 + m0) = o;
      }
    }
#pragma unroll
    for (int nt = 0; nt < 2; ++nt) {
      pe[nt] += __shfl_xor(pe[nt], 16);
      pe[nt] += __shfl_xor(pe[nt], 32);
    }
    if (lane < 16) {
#pragma unroll
      for (int nt = 0; nt < 2; ++nt)
        epart[wrow * 64 + nbase + nt * 16 + ml] = pe[nt];
    }
  }
  __syncthreads();   // C: Tbuf(t1) + epart visible

  if (tid < 64) eijL[tid] = sigm(epart[tid] + epart[64 + tid] + efold[128]);

  // ---------------- x branch: xh' = Wx^T (x) t1^T (folded weights) ---------
#pragma unroll
  for (int a = 0; a < 4; ++a)
#pragma unroll
    for (int b = 0; b < 2; ++b) acc[a][b] = zf;
  for (int kc = 0; kc < 4; ++kc) {
    s16x8 bt[2];
#pragma unroll
    for (int nt = 0; nt < 2; ++nt)
      bt[nt] = ld_frag_lds(Tbuf + (nbase + nt * 16 + ml) * 132 + kc * 32 + q * 8);
#pragma unroll
    for (int mt = 0; mt < 4; ++mt) {
      s16x8 aw = ld_frag_g(xw1p + (size_t)(kc * HID + mbase + mt * 16 + ml) * 32 + q * 8);
#pragma unroll
      for (int nt = 0; nt < 2; ++nt)
        acc[mt][nt] = __builtin_amdgcn_mfma_f32_16x16x32_bf16(aw, bt[nt], acc[mt][nt], 0, 0, 0);
    }
  }
  {
    float px[2] = {0.f, 0.f};
#pragma unroll
    for (int mt = 0; mt < 4; ++mt) {
      const int m0 = mbase + mt * 16 + q * 4;
      const f32x4 xbv = ld_f4(bxv + m0);
      const f32x4 wv2 = ld_f4(xm_w2 + m0);
#pragma unroll
      for (int nt = 0; nt < 2; ++nt)
#pragma unroll
        for (int r = 0; r < 4; ++r) {
          float v = acc[mt][nt][r] + xbv[r];
          v *= sigm(v);
          px[nt] += v * wv2[r];
        }
    }
#pragma unroll
    for (int nt = 0; nt < 2; ++nt) {
      px[nt] += __shfl_xor(px[nt], 16);
      px[nt] += __shfl_xor(px[nt], 32);
    }
    if (lane < 16) {
#pragma unroll
      for (int nt = 0; nt < 2; ++nt)
        xpart[wrow * 64 + nbase + nt * 16 + ml] = px[nt];
    }
  }
  __syncthreads();   // D: xpart + eijL visible

  if (tid < 64) {
    const float g = tanh_fast(xpart[tid] + xpart[64 + tid]);
    rxL[tid] *= g; ryL[tid] *= g; rzL[tid] *= g;   // rxL already includes invd
  }

  if (MODE == 0) {
    __syncthreads();
    const float ev = eijL[se];
    const unsigned short* tr = (const unsigned short*)Tbuf + se * 132 + sh * 32;
    float* mp = q_f32 + (size_t)sdst * HID + sh * 32;
#pragma unroll
    for (int j = 0; j < 32; ++j)
      unsafeAtomicAdd(mp + j, b2f(tr[j]) * ev);
    if (tid < 64) {
      int dn = dstL[tid];
      unsafeAtomicAdd(&s_arr[dn], eijL[tid]);
      unsafeAtomicAdd(xout + dn * 3 + 0, rxL[tid]);
      unsafeAtomicAdd(xout + dn * 3 + 1, ryL[tid]);
      unsafeAtomicAdd(xout + dn * 3 + 2, rzL[tid]);
    }
    return;
  }

  // ---------------- MODE 1: in-block segmented reduction (64 rows) ----------
  if (wv == 0) {
    const bool flag = (lane == 0) || (dstL[lane] != dstL[lane - 1]);
    const unsigned long long mask = __ballot(flag);
    const unsigned long long ltm = (1ULL << lane) - 1;
    if (flag) segstart[__popcll(mask & ltm)] = lane;
    if (lane == 0) {
      int ns = (int)__popcll(mask);
      nseg_p[0] = ns;
      segstart[ns] = 64;
    }
  }
  __syncthreads();
  const int nseg = nseg_p[0];
  if (tid < nseg) {
    const int r0 = segstart[tid], r1 = segstart[tid + 1];
    const int d  = dstL[r0];
    const int p0 = ptr[d], p1 = ptr[d + 1];
    const bool lX = p0 < e0 + r0;
    const bool rX = p1 > e0 + r1;
    segmode[tid] = (!lX && !rX) ? 0 : (rX ? 2 : 1);
  }
  __syncthreads();

  // q: per (segment, 4-col group) sum of eij*t1 — uint2 LDS reads
  for (int t = tid; t < (nseg << 5); t += 256) {
    const int s = t >> 5, c4 = (t & 31) * 4;
    const int r0 = segstart[s], r1 = segstart[s + 1];
    float a0 = 0.f, a1 = 0.f, a2 = 0.f, a3 = 0.f;
    for (int r = r0; r < r1; ++r) {
      const uint2 v = *(const uint2*)(Tbuf + r * 132 + c4);
      const float ev = eijL[r];
      a0 += __uint_as_float(v.x << 16) * ev;
      a1 += __uint_as_float(v.x & 0xffff0000u) * ev;
      a2 += __uint_as_float(v.y << 16) * ev;
      a3 += __uint_as_float(v.y & 0xffff0000u) * ev;
    }
    const int mode = segmode[s];
    if (mode == 0) {
      uint2 o;
      o.x = pk_bf16(a0, a1);
      o.y = pk_bf16(a2, a3);
      *(uint2*)(qb + (size_t)dstL[r0] * HID + c4) = o;
    } else if (mode == 2) {
      f32x4 o = {a0, a1, a2, a3};
      *(f32x4*)(tailrec + (size_t)blockIdx.x * HID + c4) = o;
    } else {
      f32x4 o = {a0, a1, a2, a3};
      *(f32x4*)(headrec + (size_t)blockIdx.x * HID + c4) = o;
    }
  }
  // x + s: per (segment, dim) sums; dim 3 = sum of eij
  for (int t = tid; t < (nseg << 2); t += 256) {
    const int s = t >> 2, d = t & 3;
    const int r0 = segstart[s], r1 = segstart[s + 1];
    float a = 0.f;
    if (d < 3) {
      const float* src = (d == 0) ? rxL : ((d == 1) ? ryL : rzL);
      for (int r = r0; r < r1; ++r) a += src[r];
    } else {
      for (int r = r0; r < r1; ++r) a += eijL[r];
    }
    const int mode = segmode[s];
    const int dn = dstL[r0];
    if (mode == 0) {
      if (d < 3) xout[dn * 3 + d] = x[dn * 3 + d] + a;
      else       s_arr[dn] = a;
    }
    else if (mode == 2) tailx[blockIdx.x * 4 + d] = a;
    else                headx[blockIdx.x * 4 + d] = a;
  }
}

// ---- node kernel (fused fix phase-0 + GEMMs; f32 h frags; Wq fold) ---------
__global__ __launch_bounds__(256, 6)
void node_kernel(bf16* __restrict__ qv, const float* __restrict__ h,
                 float* __restrict__ s_arr, const float* __restrict__ vqv,
                 const bf16* __restrict__ nw1p, const bf16* __restrict__ nw2p,
                 const float* __restrict__ nb1, const float* __restrict__ nb2,
                 const int* __restrict__ ptr,
                 const float* __restrict__ headrec, const float* __restrict__ tailrec,
                 const float* __restrict__ headx, const float* __restrict__ tailx,
                 const float* __restrict__ x, float* __restrict__ xout,
                 float* __restrict__ hout) {
  __shared__ bf16 Tbuf[64 * 132];
  const int tid = threadIdx.x;
  const int n0 = blockIdx.x * 64;

  // ---- phase 0 (sorted path only): fix spanning / deg-0 nodes of this block
  if (ptr != nullptr) {
    const int fn = n0 + (tid >> 2);
    const int fh = tid & 3;
    if (fn < N_NODES) {
      const int p0 = ptr[fn], p1 = ptr[fn + 1];
      if (p0 == p1) {
        const uint4 z = make_uint4(0u, 0u, 0u, 0u);
        uint4* qrow = (uint4*)(qv + (size_t)fn * HID + fh * 32);
        qrow[0] = z; qrow[1] = z; qrow[2] = z; qrow[3] = z;
        if (fh == 0) {
          xout[fn * 3 + 0] = x[fn * 3 + 0];
          xout[fn * 3 + 1] = x[fn * 3 + 1];
          xout[fn * 3 + 2] = x[fn * 3 + 2];
          s_arr[fn] = 0.f;
        }
      } else {
        const int B0 = p0 >> 6, B1 = (p1 - 1) >> 6;   // 64-edge blocks
        if (B0 != B1) {
          const int c0 = fh * 32;
          float a[32];
#pragma unroll
          for (int j = 0; j < 32; ++j) a[j] = 0.f;
          float xa0 = 0.f, xa1 = 0.f, xa2 = 0.f, xa3 = 0.f;
          for (int b = B0; b < B1; ++b) {
            const float* tr = tailrec + (size_t)b * HID + c0;
#pragma unroll
            for (int j8 = 0; j8 < 8; ++j8) {
              const f32x4 v = ld_f4(tr + j8 * 4);
              a[j8 * 4 + 0] += v[0]; a[j8 * 4 + 1] += v[1];
              a[j8 * 4 + 2] += v[2]; a[j8 * 4 + 3] += v[3];
            }
            if (fh == 0) {
              const f32x4 tx = ld_f4(tailx + b * 4);
              xa0 += tx[0]; xa1 += tx[1]; xa2 += tx[2]; xa3 += tx[3];
            }
          }
          const float* hr = headrec + (size_t)B1 * HID + c0;
#pragma unroll
          for (int j8 = 0; j8 < 8; ++j8) {
            const f32x4 v = ld_f4(hr + j8 * 4);
            a[j8 * 4 + 0] += v[0]; a[j8 * 4 + 1] += v[1];
            a[j8 * 4 + 2] += v[2]; a[j8 * 4 + 3] += v[3];
          }
          if (fh == 0) {
            const f32x4 hx = ld_f4(headx + B1 * 4);
            xa0 += hx[0]; xa1 += hx[1]; xa2 += hx[2]; xa3 += hx[3];
          }
          uint4* qrow = (uint4*)(qv + (size_t)fn * HID + c0);
#pragma unroll
          for (int j8 = 0; j8 < 4; ++j8) {
            uint4 o;
            o.x = pk_bf16(a[j8 * 8 + 0], a[j8 * 8 + 1]);
            o.y = pk_bf16(a[j8 * 8 + 2], a[j8 * 8 + 3]);
            o.z = pk_bf16(a[j8 * 8 + 4], a[j8 * 8 + 5]);
            o.w = pk_bf16(a[j8 * 8 + 6], a[j8 * 8 + 7]);
            qrow[j8] = o;
          }
          if (fh == 0) {
            xout[fn * 3 + 0] = x[fn * 3 + 0] + xa0;
            xout[fn * 3 + 1] = x[fn * 3 + 1] + xa1;
            xout[fn * 3 + 2] = x[fn * 3 + 2] + xa2;
            s_arr[fn] = xa3;
          }
        }
      }
    }
    __syncthreads();   // same-workgroup global writes visible to GEMM reads
  }

  const int lane = tid & 63, wv = tid >> 6;
  const int wrow = wv >> 1, wcol = wv & 1;
  const int q = lane >> 4, ml = lane & 15;
  const int mbase = wrow * 64, nbase = wcol * 32;

  int nrow[2];
#pragma unroll
  for (int nt = 0; nt < 2; ++nt) {
    int n = n0 + nbase + nt * 16 + ml;
    nrow[nt] = (n < N_NODES) ? n : (N_NODES - 1);
  }

  const f32x4 zf = {0.f, 0.f, 0.f, 0.f};
  f32x4 acc[4][2];
#pragma unroll
  for (int a = 0; a < 4; ++a)
#pragma unroll
    for (int b = 0; b < 2; ++b) acc[a][b] = zf;

#pragma unroll
  for (int c = 0; c < 8; ++c) {
    s16x8 bn[2];
#pragma unroll
    for (int nt = 0; nt < 2; ++nt) {
      if (c < 4)
        bn[nt] = ld_frag_g(qv + (size_t)nrow[nt] * HID + c * 32 + q * 8);
      else
        bn[nt] = ld_frag_f32(h + (size_t)nrow[nt] * HID + (c - 4) * 32 + q * 8);
    }
#pragma unroll
    for (int mt = 0; mt < 4; ++mt) {
      s16x8 aw = ld_frag_g(nw1p + (size_t)(c * HID + mbase + mt * 16 + ml) * 32 + q * 8);
#pragma unroll
      for (int nt = 0; nt < 2; ++nt)
        acc[mt][nt] = __builtin_amdgcn_mfma_f32_16x16x32_bf16(aw, bn[nt], acc[mt][nt], 0, 0, 0);
    }
  }
  // rank-1 bias-fold correction: acc += s[node] * vq[m]  (mi = q@W2 + s*b2)
  {
    const float sv0 = s_arr[nrow[0]], sv1 = s_arr[nrow[1]];
#pragma unroll
    for (int mt = 0; mt < 4; ++mt) {
      const int m0 = mbase + mt * 16 + q * 4;
      const f32x4 vqf = ld_f4(vqv + m0);
#pragma unroll
      for (int r = 0; r < 4; ++r) {
        acc[mt][0][r] += sv0 * vqf[r];
        acc[mt][1][r] += sv1 * vqf[r];
      }
    }
  }
#pragma unroll
  for (int mt = 0; mt < 4; ++mt) {
    const int m0 = mbase + mt * 16 + q * 4;
    const f32x4 b1v = ld_f4(nb1 + m0);
#pragma unroll
    for (int nt = 0; nt < 2; ++nt) {
      const int e = nbase + nt * 16 + ml;
      float v0 = acc[mt][nt][0] + b1v[0]; v0 *= sigm(v0);
      float v1 = acc[mt][nt][1] + b1v[1]; v1 *= sigm(v1);
      float v2 = acc[mt][nt][2] + b1v[2]; v2 *= sigm(v2);
      float v3 = acc[mt][nt][3] + b1v[3]; v3 *= sigm(v3);
      uint2 o;
      o.x = pk_bf16(v0, v1);
      o.y = pk_bf16(v2, v3);
      *(uint2*)(Tbuf + e * 132 + m0) = o;
    }
  }
  __syncthreads();
#pragma unroll
  for (int a = 0; a < 4; ++a)
#pragma unroll
    for (int b = 0; b < 2; ++b) acc[a][b] = zf;
  for (int kc = 0; kc < 4; ++kc) {
    s16x8 bt[2];
#pragma unroll
    for (int nt = 0; nt < 2; ++nt)
      bt[nt] = ld_frag_lds(Tbuf + (nbase + nt * 16 + ml) * 132 + kc * 32 + q * 8);
#pragma unroll
    for (int mt = 0; mt < 4; ++mt) {
      s16x8 aw = ld_frag_g(nw2p + (size_t)(kc * HID + mbase + mt * 16 + ml) * 32 + q * 8);
#pragma unroll
      for (int nt = 0; nt < 2; ++nt)
        acc[mt][nt] = __builtin_amdgcn_mfma_f32_16x16x32_bf16(aw, bt[nt], acc[mt][nt], 0, 0, 0);
    }
  }
#pragma unroll
  for (int mt = 0; mt < 4; ++mt) {
    const int m0 = mbase + mt * 16 + q * 4;
    const f32x4 b2v = ld_f4(nb2 + m0);
#pragma unroll
    for (int nt = 0; nt < 2; ++nt) {
      const int nn = n0 + nbase + nt * 16 + ml;
      if (nn < N_NODES) {
        const f32x4 hv = ld_f4(h + (size_t)nn * HID + m0);
        f32x4 o;
#pragma unroll
        for (int r = 0; r < 4; ++r) o[r] = hv[r] + acc[mt][nt][r] + b2v[r];
        *(f32x4*)(hout + (size_t)nn * HID + m0) = o;
      }
    }
  }
}

// ---- launcher --------------------------------------------------------------
extern "C" void kernel_launch(void* const* d_in, const int* in_sizes, int n_in,
                              void* d_out, int out_size, void* d_ws, size_t ws_size,
                              hipStream_t stream) {
  (void)in_sizes; (void)n_in; (void)out_size;
  const float* h     = (const float*)d_in[0];
  const float* x     = (const float*)d_in[1];
  const int*   eidx  = (const int*)  d_in[2];
  const float* eattr = (const float*)d_in[3];
  const float* em_w1 = (const float*)d_in[4];
  const float* em_b1 = (const float*)d_in[5];
  const float* em_w2 = (const float*)d_in[6];
  const float* em_b2 = (const float*)d_in[7];
  const float* ei_w  = (const float*)d_in[8];
  const float* ei_b  = (const float*)d_in[9];
  const float* xm_w1 = (const float*)d_in[10];
  const float* xm_b1 = (const float*)d_in[11];
  const float* xm_w2 = (const float*)d_in[12];
  const float* nm_w1 = (const float*)d_in[13];
  const float* nm_b1 = (const float*)d_in[14];
  const float* nm_w2 = (const float*)d_in[15];
  const float* nm_b2 = (const float*)d_in[16];

  float* hout = (float*)d_out;
  float* xout = hout + (size_t)N_NODES * HID;

  const int NBLK = N_EDGES / 64;               // 10000 (64-edge tiles)
  const int NPB  = (N_NODES + 63) / 64;        // 782

  char* w = (char*)d_ws;
  bf16* qb   = (bf16*)w;  w += (size_t)N_NODES * HID * 2;
  bf16* pab  = (bf16*)w;  w += (size_t)N_NODES * 256 * 2;
  bf16* w1p  = (bf16*)w;  w += 9 * HID * 32 * 2;
  bf16* xw1p = (bf16*)w;  w += 4 * HID * 32 * 2;
  bf16* nw1p = (bf16*)w;  w += 8 * HID * 32 * 2;
  bf16* nw2p = (bf16*)w;  w += 4 * HID * 32 * 2;
  float* efold = (float*)w;  w += 132 * 4;
  float* bxv   = (float*)w;  w += 128 * 4;
  float* vqv   = (float*)w;  w += 128 * 4;
  float* s_arr = (float*)w;  w += (size_t)N_NODES * 4;
  int* cnt   = (int*)w;   w += (size_t)N_NODES * 4;
  int* gbar  = (int*)w;   w += 16 * 4;
  int* work  = (int*)w;   w += (size_t)N_NODES * 4;
  int* ptr   = (int*)w;   w += (size_t)(N_NODES + 4) * 4;
  int4* esw  = (int4*)w;  w += (size_t)N_EDGES * 16;
  int* bsum  = (int*)w;   w += 256 * 4;
  int* boff  = (int*)w;   w += 256 * 4;
  float* headrec = (float*)w;  w += (size_t)NBLK * HID * 4;
  float* tailrec = (float*)w;  w += (size_t)NBLK * HID * 4;
  float* headx   = (float*)w;  w += (size_t)NBLK * 4 * 4;
  float* tailx   = (float*)w;  w += (size_t)NBLK * 4 * 4;
  float* q_f32   = (float*)w;  // fallback only
  size_t need_sorted = (size_t)(w - (char*)d_ws);
  const bool sorted = (ws_size >= need_sorted);

  if (sorted) {
    hipMemsetAsync(cnt, 0, (size_t)(N_NODES + 16) * 4, stream);   // cnt + gbar
    cvtpack_kernel<<<402 + 2500, 256, 0, stream>>>(
        em_w1, nm_w1, nm_w2, em_w2, xm_w1, em_b2, ei_w, ei_b, xm_b1,
        w1p, nw1p, nw2p, xw1p, efold, bxv, vqv, eidx + N_EDGES, cnt);
    proj_kernel<<<NPB, 256, 0, stream>>>(h, w1p, pab);
    scan_kernel<<<NBGRID, 256, 0, stream>>>(cnt, ptr, work, bsum, boff, gbar);
    scatter_kernel<<<(N_EDGES + 255) / 256, 256, 0, stream>>>(
        eidx, eidx + N_EDGES, work, esw);
    edge_kernel<1><<<NBLK, 256, 0, stream>>>(
        pab, x, nullptr, nullptr, esw, ptr, eattr, w1p, xw1p,
        em_b1, efold, bxv, xm_w2,
        nullptr, xout, qb, s_arr, headrec, tailrec, headx, tailx);
    node_kernel<<<NPB, 256, 0, stream>>>(
        qb, h, s_arr, vqv, nw1p, nw2p, nm_b1, nm_b2,
        ptr, headrec, tailrec, headx, tailx, x, xout, hout);
  } else {
    cvtpack_kernel<<<402, 256, 0, stream>>>(
        em_w1, nm_w1, nm_w2, em_w2, xm_w1, em_b2, ei_w, ei_b, xm_b1,
        w1p, nw1p, nw2p, xw1p, efold, bxv, vqv, nullptr, nullptr);
    proj_kernel<<<NPB, 256, 0, stream>>>(h, w1p, pab);
    hipMemsetAsync(q_f32, 0, (size_t)N_NODES * HID * 4, stream);
    hipMemsetAsync(s_arr, 0, (size_t)N_NODES * 4, stream);
    copy_x_kernel<<<(N_NODES * 3 + 255) / 256, 256, 0, stream>>>(x, xout, N_NODES * 3);
    edge_kernel<0><<<NBLK, 256, 0, stream>>>(
        pab, x, eidx, eidx + N_EDGES, nullptr, nullptr, eattr, w1p, xw1p,
        em_b1, efold, bxv, xm_w2,
        q_f32, xout, nullptr, s_arr, nullptr, nullptr, nullptr, nullptr);
    cvt_kernel<<<(N_NODES * HID + 255) / 256, 256, 0, stream>>>(q_f32, qb, N_NODES * HID);
    node_kernel<<<NPB, 256, 0, stream>>>(
        qb, h, s_arr, vqv, nw1p, nw2p, nm_b1, nm_b2,
        nullptr, nullptr, nullptr, nullptr, nullptr, x, xout, hout);
  }
}

// Round 11
// 388.172 us; speedup vs baseline: 1.0788x; 1.0292x over previous
//
#include <hip/hip_runtime.h>
#include <hip/hip_bf16.h>

#define N_NODES 50000
#define N_EDGES 640000
#define HID 128
#define NBGRID 196

typedef float f32x4 __attribute__((ext_vector_type(4)));
typedef short s16x8 __attribute__((ext_vector_type(8)));
typedef __hip_bfloat16 bf16;

// ---- helpers ---------------------------------------------------------------
__device__ __forceinline__ s16x8 ld_frag_lds(const bf16* p) {
  union { uint2 u[2]; s16x8 v; } r;
  r.u[0] = *(const uint2*)(p);
  r.u[1] = *(const uint2*)(p + 4);
  return r.v;
}
__device__ __forceinline__ s16x8 ld_frag_g(const bf16* p) {
  union { uint4 u; s16x8 v; } r;
  r.u = *(const uint4*)(p);
  return r.v;
}
__device__ __forceinline__ f32x4 ld_f4(const float* p) { return *(const f32x4*)p; }
// fast sigmoid: raw v_rcp (1 ulp) instead of IEEE div — saves ~3 ops/use
__device__ __forceinline__ float sigm(float v) {
  return __builtin_amdgcn_rcpf(1.f + __expf(-v));
}
__device__ __forceinline__ float tanh_fast(float x) {
  return 1.f - 2.f * __builtin_amdgcn_rcpf(__expf(2.f * x) + 1.f);
}
__device__ __forceinline__ float b2f(unsigned short u) {
  return __uint_as_float(((unsigned)u) << 16);
}
// packed f32x2 -> bf16x2 (single v_cvt_pk_bf16_f32 on gfx950)
#if defined(__has_builtin)
#if __has_builtin(__builtin_amdgcn_cvt_pk_bf16_f32)
#define HAS_PK_BF16 1
#endif
#endif
__device__ __forceinline__ unsigned pk_bf16(float a, float b) {
#ifdef HAS_PK_BF16
  typedef __bf16 bf16x2_t __attribute__((ext_vector_type(2)));
  bf16x2_t r = __builtin_amdgcn_cvt_pk_bf16_f32(a, b);
  unsigned u;
  __builtin_memcpy(&u, &r, 4);
  return u;
#else
  union { bf16 h[2]; unsigned u; } o;
  o.h[0] = __float2bfloat16(a);
  o.h[1] = __float2bfloat16(b);
  return o.u;
#endif
}
// 8 consecutive f32 -> bf16x8 frag (in-register cvt; same RTNE as cvt pass)
__device__ __forceinline__ s16x8 ld_frag_f32(const float* p) {
  f32x4 v0 = ld_f4(p), v1 = ld_f4(p + 4);
  union { unsigned u[4]; s16x8 v; } r;
  r.u[0] = pk_bf16(v0[0], v0[1]);
  r.u[1] = pk_bf16(v0[2], v0[3]);
  r.u[2] = pk_bf16(v1[0], v1[1]);
  r.u[3] = pk_bf16(v1[2], v1[3]);
  return r.v;
}

// ---- prep kernels ----------------------------------------------------------
__global__ void cvt_kernel(const float* __restrict__ src, bf16* __restrict__ dst, int n) {
  int i = blockIdx.x * 256 + threadIdx.x;
  if (i < n) dst[i] = __float2bfloat16(src[i]);
}
__global__ void copy_x_kernel(const float* __restrict__ src, float* __restrict__ dst, int n) {
  int i = blockIdx.x * 256 + threadIdx.x;
  if (i < n) dst[i] = src[i];
}
// fp32 [K x 128] -> bf16 frag pack [kc][x][kk]
__device__ __forceinline__ void pack_one(const float* __restrict__ src,
                                         bf16* __restrict__ dst, int K, int i) {
  int kk = i & 31;
  int n  = (i >> 5) & 127;
  int kc = i >> 12;
  int k  = kc * 32 + kk;
  float v = (k < K) ? src[(size_t)k * HID + n] : 0.f;
  dst[i] = __float2bfloat16(v);
}
// merged: weight packs | weight folding | dst histogram (h-cvt removed: proj
// and node convert f32->bf16 in-register now)
__global__ void cvtpack_kernel(const float* __restrict__ em_w1,
                               const float* __restrict__ nm_w1,
                               const float* __restrict__ nm_w2,
                               const float* __restrict__ em_w2,
                               const float* __restrict__ xm_w1,
                               const float* __restrict__ em_b2,
                               const float* __restrict__ ei_w,
                               const float* __restrict__ ei_b,
                               const float* __restrict__ xm_b1,
                               bf16* __restrict__ w1p,
                               bf16* __restrict__ nw1p,
                               bf16* __restrict__ nw2p,
                               bf16* __restrict__ xw1p,
                               float* __restrict__ efold,
                               float* __restrict__ bxv,
                               float* __restrict__ vqv,
                               const int* __restrict__ edst, int* __restrict__ cnt) {
  const int bid = blockIdx.x;
  const int tid = threadIdx.x;
  if (bid < 272) {
    int gid = bid * 256 + tid;
    if      (gid < 36864)  pack_one(em_w1, w1p, 273, gid);
    else if (gid < 53248)  pack_one(nm_w1 + 128 * HID, nw1p + 4 * 4096, 128, gid - 36864);
    else if (gid < 69632)  pack_one(nm_w2, nw2p, 128, gid - 53248);
    return;
  }
  if (bid < 402) {
    const int f = bid - 272;           // 0..129
    const int m = tid & 127, half = tid >> 7;
    if (f < 64) {                      // Wx rows r = f*2 + half
      const int r = f * 2 + half;
      float a = 0.f;
      const float* wr = em_w2 + r * HID;
      for (int j = 0; j < 128; ++j) a += wr[j] * xm_w1[j * HID + m];
      xw1p[(size_t)(((r >> 5) * 128 + m) * 32 + (r & 31))] = __float2bfloat16(a);
    } else if (f < 128) {              // Wq rows
      const int r = (f - 64) * 2 + half;
      float a = 0.f;
      const float* wr = em_w2 + r * HID;
      for (int j = 0; j < 128; ++j) a += wr[j] * nm_w1[j * HID + m];
      nw1p[(size_t)(((r >> 5) * 128 + m) * 32 + (r & 31))] = __float2bfloat16(a);
    } else if (f == 128) {             // efold
      if (tid < 128) {
        float a = 0.f;
        const float* wr = em_w2 + m * HID;
        for (int j = 0; j < 128; ++j) a += wr[j] * ei_w[j];
        efold[m] = a;
        if (m == 0) {
          float e = ei_b[0];
          for (int j = 0; j < 128; ++j) e += em_b2[j] * ei_w[j];
          efold[128] = e;
        }
      }
    } else {                           // bxv / vqv
      if (tid < 128) {
        float a = xm_b1[m], v = 0.f;
        for (int j = 0; j < 128; ++j) {
          a += em_b2[j] * xm_w1[j * HID + m];
          v += em_b2[j] * nm_w1[j * HID + m];
        }
        bxv[m] = a; vqv[m] = v;
      }
    }
    return;
  }
  if (cnt != nullptr) {
    int e = (bid - 402) * 256 + tid;
    if (e < N_EDGES) atomicAdd(&cnt[edst[e]], 1);
  }
}

// ---- node projection: pab[n] = [ h@W1a | h@W1b ] (bf16), f32 src, no LDS ---
__global__ __launch_bounds__(256, 4)
void proj_kernel(const float* __restrict__ h, const bf16* __restrict__ w1p,
                 bf16* __restrict__ pab) {
  const int tid = threadIdx.x;
  const int n0 = blockIdx.x * 64;
  const int lane = tid & 63, wv = tid >> 6;
  const int tbl = wv >> 1;            // 0 = Pa (W rows 0..127), 1 = Pb (128..255)
  const int mbase = (wv & 1) * 64;
  const int q = lane >> 4, ml = lane & 15;

  int nrow[4];
#pragma unroll
  for (int nt = 0; nt < 4; ++nt) {
    int n = n0 + nt * 16 + ml;
    nrow[nt] = (n < N_NODES) ? n : (N_NODES - 1);
  }

  const f32x4 zf = {0.f, 0.f, 0.f, 0.f};
  f32x4 acc[4][4];
#pragma unroll
  for (int a = 0; a < 4; ++a)
#pragma unroll
    for (int b = 0; b < 4; ++b) acc[a][b] = zf;

#pragma unroll
  for (int kc = 0; kc < 4; ++kc) {
    s16x8 bn[4];
#pragma unroll
    for (int nt = 0; nt < 4; ++nt)
      bn[nt] = ld_frag_f32(h + (size_t)nrow[nt] * HID + kc * 32 + q * 8);
#pragma unroll
    for (int mt = 0; mt < 4; ++mt) {
      s16x8 aw = ld_frag_g(w1p + (size_t)((tbl * 4 + kc) * HID + mbase + mt * 16 + ml) * 32 + q * 8);
#pragma unroll
      for (int nt = 0; nt < 4; ++nt)
        acc[mt][nt] = __builtin_amdgcn_mfma_f32_16x16x32_bf16(aw, bn[nt], acc[mt][nt], 0, 0, 0);
    }
  }
#pragma unroll
  for (int mt = 0; mt < 4; ++mt) {
    const int m0 = mbase + mt * 16 + q * 4;
#pragma unroll
    for (int nt = 0; nt < 4; ++nt) {
      const int nn = n0 + nt * 16 + ml;
      if (nn < N_NODES) {
        uint2 o;
        o.x = pk_bf16(acc[mt][nt][0], acc[mt][nt][1]);
        o.y = pk_bf16(acc[mt][nt][2], acc[mt][nt][3]);
        *(uint2*)(pab + (size_t)nn * 256 + tbl * 128 + m0) = o;
      }
    }
  }
}

// ---- fused scan (histogram/scatter stay full-width) ------------------------
__device__ __forceinline__ void gsync(int* bar, int phase) {
  __syncthreads();
  if (threadIdx.x == 0) {
    __threadfence();
    atomicAdd(&bar[phase], 1);
    while (atomicAdd(&bar[phase], 0) < NBGRID) __builtin_amdgcn_s_sleep(4);
    __threadfence();
  }
  __syncthreads();
}

__global__ __launch_bounds__(256)
void scan_kernel(const int* __restrict__ cnt, int* __restrict__ ptr,
                 int* __restrict__ work, int* __restrict__ bsum,
                 int* __restrict__ boff, int* __restrict__ bar) {
  __shared__ int s[256];
  const int tid = threadIdx.x, bid = blockIdx.x;
  const int i = bid * 256 + tid;
  int v = (i < N_NODES) ? cnt[i] : 0;
  s[tid] = v;
  __syncthreads();
  for (int off = 1; off < 256; off <<= 1) {
    int t = (tid >= off) ? s[tid - off] : 0;
    __syncthreads();
    s[tid] += t;
    __syncthreads();
  }
  const int myp = s[tid] - v;           // exclusive within block (kept in reg)
  if (tid == 255) bsum[bid] = s[255];
  gsync(bar, 0);
  if (bid == 0) {
    int v2 = (tid < NBGRID) ? bsum[tid] : 0;
    s[tid] = v2;
    __syncthreads();
    for (int off = 1; off < 256; off <<= 1) {
      int t = (tid >= off) ? s[tid - off] : 0;
      __syncthreads();
      s[tid] += t;
      __syncthreads();
    }
    if (tid < NBGRID) boff[tid] = s[tid] - v2;
    if (tid == NBGRID - 1) boff[NBGRID] = s[tid];
  }
  gsync(bar, 1);
  if (i < N_NODES) {
    int p = myp + boff[bid];
    ptr[i] = p;
    work[i] = p;
  }
  if (i == 0) ptr[N_NODES] = boff[NBGRID];
}

// ---- scatter: single int4 stream {dst, src, edge, 0} at sorted position ----
__global__ void scatter_kernel(const int* __restrict__ esrc, const int* __restrict__ edst,
                               int* __restrict__ work, int4* __restrict__ esw) {
  int e = blockIdx.x * 256 + threadIdx.x;
  if (e < N_EDGES) {
    int d = edst[e];
    int p = atomicAdd(&work[d], 1);
    esw[p] = make_int4(d, esrc[e], e, 0);
  }
}

// ---- fused edge kernel (best-known config: 128-edge tile, 256 thr, 4 waves)
// stage1: t1 = silu([I|I]x[Pa;Pb] + feat@W1c + b1) — gather-add on MFMA pipe.
// eij from folded vector; x-gate from t1@Wx; reduce q = sum eij*t1, s = sum eij.
// Config sweep r4-r10: (512,8)/(256,8) spill (VGPR cap 32); (512,4) no
// residency gain; 64-tile loses ILP (140us @49% occ vs 124us @38%). ILP
// per wave, not occupancy, bounds this kernel. Keep 128-tile/(256,4).
template<int MODE>
__global__ __launch_bounds__(256, 4)
void edge_kernel(const bf16* __restrict__ pab, const float* __restrict__ x,
                 const int* __restrict__ srci, const int* __restrict__ dsti,
                 const int4* __restrict__ esw, const int* __restrict__ ptr,
                 const float* __restrict__ eattr,
                 const bf16* __restrict__ w1p, const bf16* __restrict__ xw1p,
                 const float* __restrict__ em_b1, const float* __restrict__ efold,
                 const float* __restrict__ bxv, const float* __restrict__ xm_w2,
                 float* __restrict__ q_f32, float* __restrict__ xout,
                 bf16* __restrict__ qb, float* __restrict__ s_arr,
                 float* __restrict__ headrec, float* __restrict__ tailrec,
                 float* __restrict__ headx, float* __restrict__ tailx) {
  __shared__ float arena[9987];
  bf16*  const smem  = (bf16*)arena;          // Abuf(128x36) / Tbuf(128x132)
  float* const rxL   = arena + 8448;
  float* const ryL   = arena + 8576;
  float* const rzL   = arena + 8704;
  float* const invdL = arena + 8832;
  float* const eijL  = arena + 8960;
  float* const epart = arena + 9088;          // [2][128]
  float* const xpart = arena + 9344;          // [2][128]
  int*   const dstL     = (int*)(arena + 9600);
  int*   const segstart = (int*)(arena + 9728);
  int*   const segmode  = (int*)(arena + 9857);
  int*   const nsegA_p  = (int*)(arena + 9985);
  int*   const nseg_p   = (int*)(arena + 9986);
  bf16*  const Abuf = smem;
  bf16*  const Tbuf = smem;

  const int tid = threadIdx.x;
  const int e0  = blockIdx.x * 128;
  const int lane = tid & 63, wv = tid >> 6;
  const int wrow = wv >> 1, wcol = wv & 1;
  const int q = lane >> 4, ml = lane & 15;
  const int mbase = wrow * 64, nbase = wcol * 64;

  const int se = tid >> 1, sh = tid & 1;
  const int pos = e0 + se;
  int sdst, ssrc, eg;
  if (MODE == 1) {
    const int4 dd = esw[pos];
    sdst = dd.x; ssrc = dd.y; eg = dd.z;
  } else {
    sdst = dsti[pos]; ssrc = srci[pos]; eg = pos;
  }
  if (sh == 0) dstL[se] = sdst;

  // ---- identity-pair A-frag: A(m,k) = [k==m] + [k==m+16] -------------------
  const int jpos = ml & 7, qsel = ml >> 3;
  const bool rowsel = (q == qsel) || (q == 2 + qsel);
  union { unsigned u[4]; s16x8 v; } iden;
#pragma unroll
  for (int jj = 0; jj < 4; ++jj) {
    unsigned w0 = (rowsel && (jpos == 2 * jj))     ? 0x3F80u : 0u;
    unsigned w1 = (rowsel && (jpos == 2 * jj + 1)) ? 0x3F80u : 0u;
    iden.u[jj] = w0 | (w1 << 16);
  }

  // ---- gather raw bf16 B-frags of Pa/Pb (16B per lane per (nt,mt)) ---------
  s16x8 bfr[4][4];
#pragma unroll
  for (int nt = 0; nt < 4; ++nt) {
    const int ed = e0 + nbase + nt * 16 + ml;
    int nodei;
    if (MODE == 1) {
      const int2 dd = *(const int2*)(esw + ed);
      nodei = (q < 2) ? dd.x : dd.y;
    } else {
      nodei = (q < 2) ? dsti[ed] : srci[ed];
    }
    const bf16* pb = pab + (size_t)nodei * 256 + ((q >> 1) << 7) + mbase + ((q & 1) << 3);
#pragma unroll
    for (int mt = 0; mt < 4; ++mt)
      bfr[nt][mt] = ld_frag_g(pb + mt * 16);
  }

  // ---- edge features + rel-x (overlaps gather latency) ---------------------
  union U16 { bf16 h[16]; uint4 u[2]; } p8;
  {
    const float* ap = eattr + (size_t)eg * 16;
    if (sh == 0) {
      const float* xd = x + 3 * sdst;
      const float* xs = x + 3 * ssrc;
      float dx = xd[0] - xs[0], dy = xd[1] - xs[1], dz = xd[2] - xs[2];
      float dsq = dx * dx + dy * dy + dz * dz;
      rxL[se] = dx; ryL[se] = dy; rzL[se] = dz;
      invdL[se] = 1.f / (sqrtf(dsq + 1e-8f) + 1.f);
      p8.h[0] = __float2bfloat16(dsq);
#pragma unroll
      for (int j = 0; j < 15; ++j) p8.h[1 + j] = __float2bfloat16(ap[j]);
    } else {
      p8.h[0] = __float2bfloat16(ap[15]);
#pragma unroll
      for (int j = 1; j < 16; ++j) p8.h[j] = __float2bfloat16(0.f);
    }
  }
  // stage feat into Abuf
  {
    bf16* d = Abuf + se * 36 + sh * 16;
    ((uint2*)d)[0] = make_uint2(p8.u[0].x, p8.u[0].y);
    ((uint2*)d)[1] = make_uint2(p8.u[0].z, p8.u[0].w);
    ((uint2*)d)[2] = make_uint2(p8.u[1].x, p8.u[1].y);
    ((uint2*)d)[3] = make_uint2(p8.u[1].z, p8.u[1].w);
  }

  // ---- stage 1 part A: Pa+Pb via identity-pair MFMA (matrix pipe) ----------
  const f32x4 zf = {0.f, 0.f, 0.f, 0.f};
  f32x4 acc[4][4];
#pragma unroll
  for (int a = 0; a < 4; ++a)
#pragma unroll
    for (int b = 0; b < 4; ++b) acc[a][b] = zf;
#pragma unroll
  for (int nt = 0; nt < 4; ++nt)
#pragma unroll
    for (int mt = 0; mt < 4; ++mt)
      acc[mt][nt] = __builtin_amdgcn_mfma_f32_16x16x32_bf16(iden.v, bfr[nt][mt], acc[mt][nt], 0, 0, 0);
  __syncthreads();   // A: Abuf + dstL + rel-x visible

  // ---- stage 1 part B: feat chunk (K=32), A-frags from w1p chunk 8 ---------
  {
    s16x8 be[4];
#pragma unroll
    for (int nt = 0; nt < 4; ++nt)
      be[nt] = ld_frag_lds(Abuf + (nbase + nt * 16 + ml) * 36 + q * 8);
#pragma unroll
    for (int mt = 0; mt < 4; ++mt) {
      s16x8 aw = ld_frag_g(w1p + (size_t)(8 * HID + mbase + mt * 16 + ml) * 32 + q * 8);
#pragma unroll
      for (int nt = 0; nt < 4; ++nt)
        acc[mt][nt] = __builtin_amdgcn_mfma_f32_16x16x32_bf16(aw, be[nt], acc[mt][nt], 0, 0, 0);
    }
  }
  __syncthreads();   // B: Abuf reads done before Tbuf overwrite

  // epilogue 1: +b1, silu -> Tbuf; eij partials from folded vector (free)
  {
    float pe[4] = {0.f, 0.f, 0.f, 0.f};
#pragma unroll
    for (int mt = 0; mt < 4; ++mt) {
      const int m0 = mbase + mt * 16 + q * 4;
      const f32x4 b1v = ld_f4(em_b1 + m0);
      const f32x4 efv = ld_f4(efold + m0);
#pragma unroll
      for (int nt = 0; nt < 4; ++nt) {
        const int e = nbase + nt * 16 + ml;
        float v0 = acc[mt][nt][0] + b1v[0]; v0 *= sigm(v0);
        float v1 = acc[mt][nt][1] + b1v[1]; v1 *= sigm(v1);
        float v2 = acc[mt][nt][2] + b1v[2]; v2 *= sigm(v2);
        float v3 = acc[mt][nt][3] + b1v[3]; v3 *= sigm(v3);
        pe[nt] += v0 * efv[0] + v1 * efv[1] + v2 * efv[2] + v3 * efv[3];
        uint2 o;
        o.x = pk_bf16(v0, v1);
        o.y = pk_bf16(v2, v3);
        *(uint2*)(Tbuf + e * 132 + m0) = o;
      }
    }
#pragma unroll
    for (int nt = 0; nt < 4; ++nt) {
      pe[nt] += __shfl_xor(pe[nt], 16);
      pe[nt] += __shfl_xor(pe[nt], 32);
    }
    if (lane < 16) {
#pragma unroll
      for (int nt = 0; nt < 4; ++nt)
        epart[wrow * 128 + nbase + nt * 16 + ml] = pe[nt];
    }
  }
  __syncthreads();   // C: Tbuf(t1) + epart visible

  if (tid < 128) eijL[tid] = sigm(epart[tid] + epart[128 + tid] + efold[128]);

  // ---------------- x branch: xh' = Wx^T (x) t1^T (folded weights) ---------
#pragma unroll
  for (int a = 0; a < 4; ++a)
#pragma unroll
    for (int b = 0; b < 4; ++b) acc[a][b] = zf;
  for (int kc = 0; kc < 4; ++kc) {
    s16x8 bt[4];
#pragma unroll
    for (int nt = 0; nt < 4; ++nt)
      bt[nt] = ld_frag_lds(Tbuf + (nbase + nt * 16 + ml) * 132 + kc * 32 + q * 8);
#pragma unroll
    for (int mt = 0; mt < 4; ++mt) {
      s16x8 aw = ld_frag_g(xw1p + (size_t)(kc * HID + mbase + mt * 16 + ml) * 32 + q * 8);
#pragma unroll
      for (int nt = 0; nt < 4; ++nt)
        acc[mt][nt] = __builtin_amdgcn_mfma_f32_16x16x32_bf16(aw, bt[nt], acc[mt][nt], 0, 0, 0);
    }
  }
  {
    float px[4] = {0.f, 0.f, 0.f, 0.f};
#pragma unroll
    for (int mt = 0; mt < 4; ++mt) {
      const int m0 = mbase + mt * 16 + q * 4;
      const f32x4 xbv = ld_f4(bxv + m0);
      const f32x4 wv2 = ld_f4(xm_w2 + m0);
#pragma unroll
      for (int nt = 0; nt < 4; ++nt)
#pragma unroll
        for (int r = 0; r < 4; ++r) {
          float v = acc[mt][nt][r] + xbv[r];
          v *= sigm(v);
          px[nt] += v * wv2[r];
        }
    }
#pragma unroll
    for (int nt = 0; nt < 4; ++nt) {
      px[nt] += __shfl_xor(px[nt], 16);
      px[nt] += __shfl_xor(px[nt], 32);
    }
    if (lane < 16) {
#pragma unroll
      for (int nt = 0; nt < 4; ++nt)
        xpart[wrow * 128 + nbase + nt * 16 + ml] = px[nt];
    }
  }
  __syncthreads();   // D: xpart + eijL visible

  if (tid < 128) {
    float g  = tanh_fast(xpart[tid] + xpart[128 + tid]);
    float sc = invdL[tid] * g;
    rxL[tid] *= sc; ryL[tid] *= sc; rzL[tid] *= sc;
  }

  if (MODE == 0) {
    __syncthreads();
    const float ev = eijL[se];
    const unsigned short* tr = (const unsigned short*)Tbuf + se * 132 + sh * 64;
    float* mp = q_f32 + (size_t)sdst * HID + sh * 64;
#pragma unroll
    for (int j = 0; j < 64; ++j)
      unsafeAtomicAdd(mp + j, b2f(tr[j]) * ev);
    if (tid < 128) {
      int dn = dstL[tid];
      unsafeAtomicAdd(&s_arr[dn], eijL[tid]);
      unsafeAtomicAdd(xout + dn * 3 + 0, rxL[tid]);
      unsafeAtomicAdd(xout + dn * 3 + 1, ryL[tid]);
      unsafeAtomicAdd(xout + dn * 3 + 2, rzL[tid]);
    }
    return;
  }

  // ---------------- MODE 1: in-block segmented reduction --------------------
  const bool flag = (tid < 128) && (tid == 0 || dstL[tid] != dstL[tid - 1]);
  const unsigned long long mask = __ballot(flag);
  const unsigned long long ltm = (1ULL << lane) - 1;
  if (wv == 0) {
    if (lane == 0) nsegA_p[0] = (int)__popcll(mask);
    if (flag) segstart[__popcll(mask & ltm)] = tid;
  }
  __syncthreads();
  if (wv == 1) {
    const int base = nsegA_p[0];
    if (flag) segstart[base + __popcll(mask & ltm)] = tid;
    if (lane == 0) {
      int ns = base + (int)__popcll(mask);
      nseg_p[0] = ns;
      segstart[ns] = 128;
    }
  }
  __syncthreads();
  const int nseg = nseg_p[0];
  if (tid < nseg) {
    const int r0 = segstart[tid], r1 = segstart[tid + 1];
    const int d  = dstL[r0];
    const int p0 = ptr[d], p1 = ptr[d + 1];
    const bool lX = p0 < e0 + r0;
    const bool rX = p1 > e0 + r1;
    segmode[tid] = (!lX && !rX) ? 0 : (rX ? 2 : 1);
  }
  __syncthreads();

  // q: per (segment, 4-col group) sum of eij*t1 — uint2 LDS reads
  for (int t = tid; t < (nseg << 5); t += 256) {
    const int s = t >> 5, c4 = (t & 31) * 4;
    const int r0 = segstart[s], r1 = segstart[s + 1];
    float a0 = 0.f, a1 = 0.f, a2 = 0.f, a3 = 0.f;
    for (int r = r0; r < r1; ++r) {
      const uint2 v = *(const uint2*)(Tbuf + r * 132 + c4);
      const float ev = eijL[r];
      a0 += __uint_as_float(v.x << 16) * ev;
      a1 += __uint_as_float(v.x & 0xffff0000u) * ev;
      a2 += __uint_as_float(v.y << 16) * ev;
      a3 += __uint_as_float(v.y & 0xffff0000u) * ev;
    }
    const int mode = segmode[s];
    if (mode == 0) {
      uint2 o;
      o.x = pk_bf16(a0, a1);
      o.y = pk_bf16(a2, a3);
      *(uint2*)(qb + (size_t)dstL[r0] * HID + c4) = o;
    } else if (mode == 2) {
      f32x4 o = {a0, a1, a2, a3};
      *(f32x4*)(tailrec + (size_t)blockIdx.x * HID + c4) = o;
    } else {
      f32x4 o = {a0, a1, a2, a3};
      *(f32x4*)(headrec + (size_t)blockIdx.x * HID + c4) = o;
    }
  }
  // x + s: per (segment, dim) sums; dim 3 = sum of eij
  for (int t = tid; t < (nseg << 2); t += 256) {
    const int s = t >> 2, d = t & 3;
    const int r0 = segstart[s], r1 = segstart[s + 1];
    float a = 0.f;
    if (d < 3) {
      const float* src = (d == 0) ? rxL : ((d == 1) ? ryL : rzL);
      for (int r = r0; r < r1; ++r) a += src[r];
    } else {
      for (int r = r0; r < r1; ++r) a += eijL[r];
    }
    const int mode = segmode[s];
    const int dn = dstL[r0];
    if (mode == 0) {
      if (d < 3) xout[dn * 3 + d] = x[dn * 3 + d] + a;
      else       s_arr[dn] = a;
    }
    else if (mode == 2) tailx[blockIdx.x * 4 + d] = a;
    else                headx[blockIdx.x * 4 + d] = a;
  }
}

// ---- node kernel (fused fix phase-0 + GEMMs; f32 h frags; Wq fold) ---------
__global__ __launch_bounds__(256, 6)
void node_kernel(bf16* __restrict__ qv, const float* __restrict__ h,
                 float* __restrict__ s_arr, const float* __restrict__ vqv,
                 const bf16* __restrict__ nw1p, const bf16* __restrict__ nw2p,
                 const float* __restrict__ nb1, const float* __restrict__ nb2,
                 const int* __restrict__ ptr,
                 const float* __restrict__ headrec, const float* __restrict__ tailrec,
                 const float* __restrict__ headx, const float* __restrict__ tailx,
                 const float* __restrict__ x, float* __restrict__ xout,
                 float* __restrict__ hout) {
  __shared__ bf16 Tbuf[64 * 132];
  const int tid = threadIdx.x;
  const int n0 = blockIdx.x * 64;

  // ---- phase 0 (sorted path only): fix spanning / deg-0 nodes of this block
  if (ptr != nullptr) {
    const int fn = n0 + (tid >> 2);
    const int fh = tid & 3;
    if (fn < N_NODES) {
      const int p0 = ptr[fn], p1 = ptr[fn + 1];
      if (p0 == p1) {
        const uint4 z = make_uint4(0u, 0u, 0u, 0u);
        uint4* qrow = (uint4*)(qv + (size_t)fn * HID + fh * 32);
        qrow[0] = z; qrow[1] = z; qrow[2] = z; qrow[3] = z;
        if (fh == 0) {
          xout[fn * 3 + 0] = x[fn * 3 + 0];
          xout[fn * 3 + 1] = x[fn * 3 + 1];
          xout[fn * 3 + 2] = x[fn * 3 + 2];
          s_arr[fn] = 0.f;
        }
      } else {
        const int B0 = p0 >> 7, B1 = (p1 - 1) >> 7;   // 128-edge blocks
        if (B0 != B1) {
          const int c0 = fh * 32;
          float a[32];
#pragma unroll
          for (int j = 0; j < 32; ++j) a[j] = 0.f;
          float xa0 = 0.f, xa1 = 0.f, xa2 = 0.f, xa3 = 0.f;
          for (int b = B0; b < B1; ++b) {
            const float* tr = tailrec + (size_t)b * HID + c0;
#pragma unroll
            for (int j8 = 0; j8 < 8; ++j8) {
              const f32x4 v = ld_f4(tr + j8 * 4);
              a[j8 * 4 + 0] += v[0]; a[j8 * 4 + 1] += v[1];
              a[j8 * 4 + 2] += v[2]; a[j8 * 4 + 3] += v[3];
            }
            if (fh == 0) {
              const f32x4 tx = ld_f4(tailx + b * 4);
              xa0 += tx[0]; xa1 += tx[1]; xa2 += tx[2]; xa3 += tx[3];
            }
          }
          const float* hr = headrec + (size_t)B1 * HID + c0;
#pragma unroll
          for (int j8 = 0; j8 < 8; ++j8) {
            const f32x4 v = ld_f4(hr + j8 * 4);
            a[j8 * 4 + 0] += v[0]; a[j8 * 4 + 1] += v[1];
            a[j8 * 4 + 2] += v[2]; a[j8 * 4 + 3] += v[3];
          }
          if (fh == 0) {
            const f32x4 hx = ld_f4(headx + B1 * 4);
            xa0 += hx[0]; xa1 += hx[1]; xa2 += hx[2]; xa3 += hx[3];
          }
          uint4* qrow = (uint4*)(qv + (size_t)fn * HID + c0);
#pragma unroll
          for (int j8 = 0; j8 < 4; ++j8) {
            uint4 o;
            o.x = pk_bf16(a[j8 * 8 + 0], a[j8 * 8 + 1]);
            o.y = pk_bf16(a[j8 * 8 + 2], a[j8 * 8 + 3]);
            o.z = pk_bf16(a[j8 * 8 + 4], a[j8 * 8 + 5]);
            o.w = pk_bf16(a[j8 * 8 + 6], a[j8 * 8 + 7]);
            qrow[j8] = o;
          }
          if (fh == 0) {
            xout[fn * 3 + 0] = x[fn * 3 + 0] + xa0;
            xout[fn * 3 + 1] = x[fn * 3 + 1] + xa1;
            xout[fn * 3 + 2] = x[fn * 3 + 2] + xa2;
            s_arr[fn] = xa3;
          }
        }
      }
    }
    __syncthreads();   // same-workgroup global writes visible to GEMM reads
  }

  const int lane = tid & 63, wv = tid >> 6;
  const int wrow = wv >> 1, wcol = wv & 1;
  const int q = lane >> 4, ml = lane & 15;
  const int mbase = wrow * 64, nbase = wcol * 32;

  int nrow[2];
#pragma unroll
  for (int nt = 0; nt < 2; ++nt) {
    int n = n0 + nbase + nt * 16 + ml;
    nrow[nt] = (n < N_NODES) ? n : (N_NODES - 1);
  }

  const f32x4 zf = {0.f, 0.f, 0.f, 0.f};
  f32x4 acc[4][2];
#pragma unroll
  for (int a = 0; a < 4; ++a)
#pragma unroll
    for (int b = 0; b < 2; ++b) acc[a][b] = zf;

#pragma unroll
  for (int c = 0; c < 8; ++c) {
    s16x8 bn[2];
#pragma unroll
    for (int nt = 0; nt < 2; ++nt) {
      if (c < 4)
        bn[nt] = ld_frag_g(qv + (size_t)nrow[nt] * HID + c * 32 + q * 8);
      else
        bn[nt] = ld_frag_f32(h + (size_t)nrow[nt] * HID + (c - 4) * 32 + q * 8);
    }
#pragma unroll
    for (int mt = 0; mt < 4; ++mt) {
      s16x8 aw = ld_frag_g(nw1p + (size_t)(c * HID + mbase + mt * 16 + ml) * 32 + q * 8);
#pragma unroll
      for (int nt = 0; nt < 2; ++nt)
        acc[mt][nt] = __builtin_amdgcn_mfma_f32_16x16x32_bf16(aw, bn[nt], acc[mt][nt], 0, 0, 0);
    }
  }
  // rank-1 bias-fold correction: acc += s[node] * vq[m]  (mi = q@W2 + s*b2)
  {
    const float sv0 = s_arr[nrow[0]], sv1 = s_arr[nrow[1]];
#pragma unroll
    for (int mt = 0; mt < 4; ++mt) {
      const int m0 = mbase + mt * 16 + q * 4;
      const f32x4 vqf = ld_f4(vqv + m0);
#pragma unroll
      for (int r = 0; r < 4; ++r) {
        acc[mt][0][r] += sv0 * vqf[r];
        acc[mt][1][r] += sv1 * vqf[r];
      }
    }
  }
#pragma unroll
  for (int mt = 0; mt < 4; ++mt) {
    const int m0 = mbase + mt * 16 + q * 4;
    const f32x4 b1v = ld_f4(nb1 + m0);
#pragma unroll
    for (int nt = 0; nt < 2; ++nt) {
      const int e = nbase + nt * 16 + ml;
      float v0 = acc[mt][nt][0] + b1v[0]; v0 *= sigm(v0);
      float v1 = acc[mt][nt][1] + b1v[1]; v1 *= sigm(v1);
      float v2 = acc[mt][nt][2] + b1v[2]; v2 *= sigm(v2);
      float v3 = acc[mt][nt][3] + b1v[3]; v3 *= sigm(v3);
      uint2 o;
      o.x = pk_bf16(v0, v1);
      o.y = pk_bf16(v2, v3);
      *(uint2*)(Tbuf + e * 132 + m0) = o;
    }
  }
  __syncthreads();
#pragma unroll
  for (int a = 0; a < 4; ++a)
#pragma unroll
    for (int b = 0; b < 2; ++b) acc[a][b] = zf;
  for (int kc = 0; kc < 4; ++kc) {
    s16x8 bt[2];
#pragma unroll
    for (int nt = 0; nt < 2; ++nt)
      bt[nt] = ld_frag_lds(Tbuf + (nbase + nt * 16 + ml) * 132 + kc * 32 + q * 8);
#pragma unroll
    for (int mt = 0; mt < 4; ++mt) {
      s16x8 aw = ld_frag_g(nw2p + (size_t)(kc * HID + mbase + mt * 16 + ml) * 32 + q * 8);
#pragma unroll
      for (int nt = 0; nt < 2; ++nt)
        acc[mt][nt] = __builtin_amdgcn_mfma_f32_16x16x32_bf16(aw, bt[nt], acc[mt][nt], 0, 0, 0);
    }
  }
#pragma unroll
  for (int mt = 0; mt < 4; ++mt) {
    const int m0 = mbase + mt * 16 + q * 4;
    const f32x4 b2v = ld_f4(nb2 + m0);
#pragma unroll
    for (int nt = 0; nt < 2; ++nt) {
      const int nn = n0 + nbase + nt * 16 + ml;
      if (nn < N_NODES) {
        const f32x4 hv = ld_f4(h + (size_t)nn * HID + m0);
        f32x4 o;
#pragma unroll
        for (int r = 0; r < 4; ++r) o[r] = hv[r] + acc[mt][nt][r] + b2v[r];
        *(f32x4*)(hout + (size_t)nn * HID + m0) = o;
      }
    }
  }
}

// ---- launcher --------------------------------------------------------------
extern "C" void kernel_launch(void* const* d_in, const int* in_sizes, int n_in,
                              void* d_out, int out_size, void* d_ws, size_t ws_size,
                              hipStream_t stream) {
  (void)in_sizes; (void)n_in; (void)out_size;
  const float* h     = (const float*)d_in[0];
  const float* x     = (const float*)d_in[1];
  const int*   eidx  = (const int*)  d_in[2];
  const float* eattr = (const float*)d_in[3];
  const float* em_w1 = (const float*)d_in[4];
  const float* em_b1 = (const float*)d_in[5];
  const float* em_w2 = (const float*)d_in[6];
  const float* em_b2 = (const float*)d_in[7];
  const float* ei_w  = (const float*)d_in[8];
  const float* ei_b  = (const float*)d_in[9];
  const float* xm_w1 = (const float*)d_in[10];
  const float* xm_b1 = (const float*)d_in[11];
  const float* xm_w2 = (const float*)d_in[12];
  const float* nm_w1 = (const float*)d_in[13];
  const float* nm_b1 = (const float*)d_in[14];
  const float* nm_w2 = (const float*)d_in[15];
  const float* nm_b2 = (const float*)d_in[16];

  float* hout = (float*)d_out;
  float* xout = hout + (size_t)N_NODES * HID;

  const int NBLK = N_EDGES / 128;              // 5000
  const int NPB  = (N_NODES + 63) / 64;        // 782

  char* w = (char*)d_ws;
  bf16* qb   = (bf16*)w;  w += (size_t)N_NODES * HID * 2;
  bf16* pab  = (bf16*)w;  w += (size_t)N_NODES * 256 * 2;
  bf16* w1p  = (bf16*)w;  w += 9 * HID * 32 * 2;
  bf16* xw1p = (bf16*)w;  w += 4 * HID * 32 * 2;
  bf16* nw1p = (bf16*)w;  w += 8 * HID * 32 * 2;
  bf16* nw2p = (bf16*)w;  w += 4 * HID * 32 * 2;
  float* efold = (float*)w;  w += 132 * 4;
  float* bxv   = (float*)w;  w += 128 * 4;
  float* vqv   = (float*)w;  w += 128 * 4;
  float* s_arr = (float*)w;  w += (size_t)N_NODES * 4;
  int* cnt   = (int*)w;   w += (size_t)N_NODES * 4;
  int* gbar  = (int*)w;   w += 16 * 4;
  int* work  = (int*)w;   w += (size_t)N_NODES * 4;
  int* ptr   = (int*)w;   w += (size_t)(N_NODES + 4) * 4;
  int4* esw  = (int4*)w;  w += (size_t)N_EDGES * 16;
  int* bsum  = (int*)w;   w += 256 * 4;
  int* boff  = (int*)w;   w += 256 * 4;
  float* headrec = (float*)w;  w += (size_t)NBLK * HID * 4;
  float* tailrec = (float*)w;  w += (size_t)NBLK * HID * 4;
  float* headx   = (float*)w;  w += (size_t)NBLK * 4 * 4;
  float* tailx   = (float*)w;  w += (size_t)NBLK * 4 * 4;
  float* q_f32   = (float*)w;  // fallback only
  size_t need_sorted = (size_t)(w - (char*)d_ws);
  const bool sorted = (ws_size >= need_sorted);

  if (sorted) {
    hipMemsetAsync(cnt, 0, (size_t)(N_NODES + 16) * 4, stream);   // cnt + gbar
    cvtpack_kernel<<<402 + 2500, 256, 0, stream>>>(
        em_w1, nm_w1, nm_w2, em_w2, xm_w1, em_b2, ei_w, ei_b, xm_b1,
        w1p, nw1p, nw2p, xw1p, efold, bxv, vqv, eidx + N_EDGES, cnt);
    proj_kernel<<<NPB, 256, 0, stream>>>(h, w1p, pab);
    scan_kernel<<<NBGRID, 256, 0, stream>>>(cnt, ptr, work, bsum, boff, gbar);
    scatter_kernel<<<(N_EDGES + 255) / 256, 256, 0, stream>>>(
        eidx, eidx + N_EDGES, work, esw);
    edge_kernel<1><<<NBLK, 256, 0, stream>>>(
        pab, x, nullptr, nullptr, esw, ptr, eattr, w1p, xw1p,
        em_b1, efold, bxv, xm_w2,
        nullptr, xout, qb, s_arr, headrec, tailrec, headx, tailx);
    node_kernel<<<NPB, 256, 0, stream>>>(
        qb, h, s_arr, vqv, nw1p, nw2p, nm_b1, nm_b2,
        ptr, headrec, tailrec, headx, tailx, x, xout, hout);
  } else {
    cvtpack_kernel<<<402, 256, 0, stream>>>(
        em_w1, nm_w1, nm_w2, em_w2, xm_w1, em_b2, ei_w, ei_b, xm_b1,
        w1p, nw1p, nw2p, xw1p, efold, bxv, vqv, nullptr, nullptr);
    proj_kernel<<<NPB, 256, 0, stream>>>(h, w1p, pab);
    hipMemsetAsync(q_f32, 0, (size_t)N_NODES * HID * 4, stream);
    hipMemsetAsync(s_arr, 0, (size_t)N_NODES * 4, stream);
    copy_x_kernel<<<(N_NODES * 3 + 255) / 256, 256, 0, stream>>>(x, xout, N_NODES * 3);
    edge_kernel<0><<<NBLK, 256, 0, stream>>>(
        pab, x, eidx, eidx + N_EDGES, nullptr, nullptr, eattr, w1p, xw1p,
        em_b1, efold, bxv, xm_w2,
        q_f32, xout, nullptr, s_arr, nullptr, nullptr, nullptr, nullptr);
    cvt_kernel<<<(N_NODES * HID + 255) / 256, 256, 0, stream>>>(q_f32, qb, N_NODES * HID);
    node_kernel<<<NPB, 256, 0, stream>>>(
        qb, h, s_arr, vqv, nw1p, nw2p, nm_b1, nm_b2,
        nullptr, nullptr, nullptr, nullptr, nullptr, x, xout, hout);
  }
}